// Round 12
// baseline (506.954 us; speedup 1.0000x reference)
//
#include <hip/hip_runtime.h>
#include <math.h>

#define LN_EPS 1e-5f
#define CAPB 2816          // bucket capacity: mean 2048 + ~17 sigma

typedef __attribute__((ext_vector_type(8))) __bf16 bf16x8;
typedef __attribute__((ext_vector_type(4))) float f32x4;

__device__ inline float bf2f(unsigned short u) {
  union { unsigned int i; float f; } x; x.i = ((unsigned int)u) << 16; return x.f;
}
__device__ inline unsigned short f2bf(float f) {
  union { float f; unsigned int i; } x; x.f = f;
  unsigned int r = (x.i + 0x7FFFu + ((x.i >> 16) & 1u)) >> 16;   // RNE
  return (unsigned short)r;
}
__device__ inline void gload_lds16(const void* g, void* l) {
  __builtin_amdgcn_global_load_lds((const __attribute__((address_space(1))) void*)g,
                                   (__attribute__((address_space(3))) void*)l, 16, 0, 0);
}

// ------- front: to_bf16 ∪ bucket-counter zero ∪ all weight transposes + bias concat -------
__global__ __launch_bounds__(256)
void front(const float* __restrict__ x, unsigned short* __restrict__ xbf, long n,
           int* __restrict__ bcnt, int nbuck, int* __restrict__ ovf_cnt, int gA,
           const float* qW, const float* kW, const float* vW, const float* oW,
           const float* f1W, const float* f2W,
           unsigned short* qkvWt, unsigned short* oWt,
           unsigned short* f1Wt, unsigned short* f2Wt,
           const float* qb, const float* kb, const float* vb, float* qkvbias) {
  const int b = blockIdx.x;
  const int tid = threadIdx.x;
  if (b < gA) {                       // f32 -> bf16
    long i = ((long)b * 256 + tid) * 4;
    if (i >= n) return;
    float4 v = *(const float4*)&x[i];
    ushort4 o = { f2bf(v.x), f2bf(v.y), f2bf(v.z), f2bf(v.w) };
    *(ushort4*)&xbf[i] = o;
    return;
  }
  if (b == gA) {                      // zero bucket counters + overflow counter
    for (int i = tid; i < nbuck; i += 256) bcnt[i] = 0;
    if (tid == 0) *ovf_cnt = 0;
    return;
  }
  const int t = b - gA - 1;           // weight prep tiles
  if (t == 192) {
    int i = tid;
    if (i < 128) { qkvbias[i] = qb[i]; qkvbias[128 + i] = kb[i]; }
    else if (i < 256) qkvbias[256 + (i - 128)] = vb[i - 128];
    return;
  }
  const float* W; unsigned short* Wt; int K, M, lt;
  if (t < 64)       { K = 128; M = 128; lt = t & 15;
    if (t < 16)      { W = qW; Wt = qkvWt; }
    else if (t < 32) { W = kW; Wt = qkvWt + 16384; }
    else if (t < 48) { W = vW; Wt = qkvWt + 32768; }
    else             { W = oW; Wt = oWt; } }
  else if (t < 128) { K = 128; M = 512; lt = t - 64; W = f1W; Wt = f1Wt; }
  else              { K = 512; M = 128; lt = t - 128; W = f2W; Wt = f2Wt; }
  const int ktiles = K >> 5;
  const int k0 = (lt % ktiles) * 32, m0 = (lt / ktiles) * 32;
  __shared__ float tb[32][33];
  const int tx = tid & 31, ty = tid >> 5;  // 32 x 8
#pragma unroll
  for (int i = 0; i < 32; i += 8)
    tb[ty + i][tx] = W[(size_t)(k0 + ty + i) * M + m0 + tx];
  __syncthreads();
#pragma unroll
  for (int i = 0; i < 32; i += 8)
    Wt[(size_t)(m0 + ty + i) * K + k0 + tx] = f2bf(tb[tx][ty + i]);
}

// ---------------- bf16 MFMA GEMM: C[N,M] = A[N,K] @ Wt[M,K]^T + bias ----------------
template<bool OBF>
__global__ __launch_bounds__(256)
void gemm_mfma(const unsigned short* __restrict__ A, const unsigned short* __restrict__ Wt,
               const float* __restrict__ bias, void* __restrict__ Cout,
               int Nr, int K, int M) {
  __shared__ __align__(16) unsigned short As[128 * 64];
  __shared__ __align__(16) unsigned short Bs[128 * 64];
  const int tid = threadIdx.x;
  const int bm = blockIdx.x * 128, bn = blockIdx.y * 128;
  const int lane = tid & 63;
  const int wr = (tid >> 6) >> 1, wc = (tid >> 6) & 1;
  f32x4 acc[4][4] = {};
  const int nkt = K >> 6;
  for (int kt = 0; kt < nkt; ++kt) {
#pragma unroll
    for (int i = 0; i < 4; ++i) {
      int c = tid + i * 256;
      int row = c >> 3;
      int j = (c & 7) ^ (row & 7);
      int ar = bm + row; ar = ar < Nr ? ar : Nr - 1;
      gload_lds16(A + (size_t)ar * K + kt * 64 + j * 8, As + (size_t)c * 8);
      gload_lds16(Wt + (size_t)(bn + row) * K + kt * 64 + j * 8, Bs + (size_t)c * 8);
    }
    __syncthreads();
#pragma unroll
    for (int ks = 0; ks < 2; ++ks) {
      bf16x8 af[4], bfr[4];
#pragma unroll
      for (int f = 0; f < 4; ++f) {
        int rowa = wr * 64 + f * 16 + (lane & 15);
        int ja = (ks * 4 + (lane >> 4)) ^ (rowa & 7);
        af[f] = *(const bf16x8*)(As + rowa * 64 + ja * 8);
        int rowb = wc * 64 + f * 16 + (lane & 15);
        int jb = (ks * 4 + (lane >> 4)) ^ (rowb & 7);
        bfr[f] = *(const bf16x8*)(Bs + rowb * 64 + jb * 8);
      }
#pragma unroll
      for (int fr = 0; fr < 4; ++fr)
#pragma unroll
        for (int fc = 0; fc < 4; ++fc)
          acc[fr][fc] = __builtin_amdgcn_mfma_f32_16x16x32_bf16(af[fr], bfr[fc], acc[fr][fc], 0, 0, 0);
    }
    __syncthreads();
  }
#pragma unroll
  for (int fr = 0; fr < 4; ++fr) {
#pragma unroll
    for (int j = 0; j < 4; ++j) {
      int row = bm + wr * 64 + fr * 16 + (lane >> 4) * 4 + j;
      if (row < Nr) {
#pragma unroll
        for (int fc = 0; fc < 4; ++fc) {
          int col = bn + wc * 64 + fc * 16 + (lane & 15);
          float v = acc[fr][fc][j] + bias[col];
          if (OBF) ((unsigned short*)Cout)[(size_t)row * M + col] = f2bf(v);
          else     ((float*)Cout)[(size_t)row * M + col] = v;
        }
      }
    }
  }
}

// ------- bf16 MFMA GEMM (M=128) fused with y = LN(res + A@Wt^T + bias) -------
template<bool WF32, bool WBF, bool RESBF>
__global__ __launch_bounds__(256)
void gemm_ln(const unsigned short* __restrict__ A, const unsigned short* __restrict__ Wt,
             const float* __restrict__ bias, const void* __restrict__ res,
             const float* __restrict__ g, const float* __restrict__ b,
             float* __restrict__ y, unsigned short* __restrict__ ybf, int Nr, int K) {
  __shared__ __align__(16) unsigned short As[128 * 64];
  __shared__ __align__(16) unsigned short Bs[128 * 64];
  __shared__ float pls[128][2], plss[128][2];
  const int tid = threadIdx.x;
  const int bm = blockIdx.x * 128;
  const int lane = tid & 63;
  const int wr = (tid >> 6) >> 1, wc = (tid >> 6) & 1;
  f32x4 acc[4][4] = {};
  const int nkt = K >> 6;
  for (int kt = 0; kt < nkt; ++kt) {
#pragma unroll
    for (int i = 0; i < 4; ++i) {
      int c = tid + i * 256;
      int row = c >> 3;
      int j = (c & 7) ^ (row & 7);
      int ar = bm + row; ar = ar < Nr ? ar : Nr - 1;
      gload_lds16(A + (size_t)ar * K + kt * 64 + j * 8, As + (size_t)c * 8);
      gload_lds16(Wt + (size_t)row * K + kt * 64 + j * 8, Bs + (size_t)c * 8);
    }
    __syncthreads();
#pragma unroll
    for (int ks = 0; ks < 2; ++ks) {
      bf16x8 af[4], bfr[4];
#pragma unroll
      for (int f = 0; f < 4; ++f) {
        int rowa = wr * 64 + f * 16 + (lane & 15);
        int ja = (ks * 4 + (lane >> 4)) ^ (rowa & 7);
        af[f] = *(const bf16x8*)(As + rowa * 64 + ja * 8);
        int rowb = wc * 64 + f * 16 + (lane & 15);
        int jb = (ks * 4 + (lane >> 4)) ^ (rowb & 7);
        bfr[f] = *(const bf16x8*)(Bs + rowb * 64 + jb * 8);
      }
#pragma unroll
      for (int fr = 0; fr < 4; ++fr)
#pragma unroll
        for (int fc = 0; fc < 4; ++fc)
          acc[fr][fc] = __builtin_amdgcn_mfma_f32_16x16x32_bf16(af[fr], bfr[fc], acc[fr][fc], 0, 0, 0);
    }
    __syncthreads();
  }
#pragma unroll
  for (int fr = 0; fr < 4; ++fr) {
#pragma unroll
    for (int j = 0; j < 4; ++j) {
      const int rl = wr * 64 + fr * 16 + (lane >> 4) * 4 + j;
      const int row = bm + rl;
      const int rowc = row < Nr ? row : Nr - 1;
      float s = 0.f, ss = 0.f;
#pragma unroll
      for (int fc = 0; fc < 4; ++fc) {
        int col = wc * 64 + fc * 16 + (lane & 15);
        float rv = RESBF ? bf2f(((const unsigned short*)res)[(size_t)rowc * 128 + col])
                         : ((const float*)res)[(size_t)rowc * 128 + col];
        float val = acc[fr][fc][j] + bias[col] + rv;
        acc[fr][fc][j] = val;
        s += val; ss += val * val;
      }
      s += __shfl_xor(s, 1); ss += __shfl_xor(ss, 1);
      s += __shfl_xor(s, 2); ss += __shfl_xor(ss, 2);
      s += __shfl_xor(s, 4); ss += __shfl_xor(ss, 4);
      s += __shfl_xor(s, 8); ss += __shfl_xor(ss, 8);
      if ((lane & 15) == 0) { pls[rl][wc] = s; plss[rl][wc] = ss; }
    }
  }
  __syncthreads();
#pragma unroll
  for (int fr = 0; fr < 4; ++fr) {
#pragma unroll
    for (int j = 0; j < 4; ++j) {
      const int rl = wr * 64 + fr * 16 + (lane >> 4) * 4 + j;
      const int row = bm + rl;
      if (row >= Nr) continue;
      const float S = pls[rl][0] + pls[rl][1];
      const float SS = plss[rl][0] + plss[rl][1];
      const float mu = S * (1.f / 128.f);
      const float inv = rsqrtf(SS * (1.f / 128.f) - mu * mu + LN_EPS);
#pragma unroll
      for (int fc = 0; fc < 4; ++fc) {
        int col = wc * 64 + fc * 16 + (lane & 15);
        float o = (acc[fr][fc][j] - mu) * inv * g[col] + b[col];
        if (WF32) y[(size_t)row * 128 + col] = o;
        if (WBF)  ybf[(size_t)row * 128 + col] = f2bf(o);
      }
    }
  }
}

// ------- edge pass 1: bias GEMV + bin (src,dst)+bias into coarse dst buckets -------
__global__ __launch_bounds__(256)
void edge_bin(const int* __restrict__ ei, const float* __restrict__ ea,
              const float* __restrict__ eW, const float* __restrict__ eb,
              int* __restrict__ bcnt, uint2* __restrict__ sd_arr, uint4* __restrict__ bias_arr,
              int* __restrict__ ovf_cnt, uint2* __restrict__ ovf_sd, uint4* __restrict__ ovf_bias,
              int E) {
  __shared__ float ews[256];
  __shared__ float ebs[8];
  const int tid = threadIdx.x;
  if (tid < 256) ews[tid] = eW[tid];
  if (tid < 8) ebs[tid] = eb[tid];
  __syncthreads();
  int e = blockIdx.x * 256 + tid;
  if (e >= E) return;
  const int src = ei[e], dst = ei[E + e];
  float bias[8];
#pragma unroll
  for (int h = 0; h < 8; ++h) bias[h] = ebs[h];
#pragma unroll
  for (int i4 = 0; i4 < 8; ++i4) {
    float4 a = *(const float4*)&ea[(size_t)e * 32 + i4 * 4];
    float av[4] = {a.x, a.y, a.z, a.w};
#pragma unroll
    for (int j = 0; j < 4; ++j)
#pragma unroll
      for (int h = 0; h < 8; ++h) bias[h] += av[j] * ews[(i4 * 4 + j) * 8 + h];
  }
  union { unsigned short us[8]; uint4 v; } pk;
#pragma unroll
  for (int h = 0; h < 8; ++h) pk.us[h] = f2bf(bias[h]);
  const int b = dst >> 7;
  const int p = atomicAdd(&bcnt[b], 1);
  if (p < CAPB) {
    sd_arr[(size_t)b * CAPB + p] = make_uint2((unsigned)src, (unsigned)dst);
    bias_arr[(size_t)b * CAPB + p] = pk.v;
  } else {
    int o = atomicAdd(ovf_cnt, 1);
    if (o < 4096) { ovf_sd[o] = make_uint2((unsigned)src, (unsigned)dst); ovf_bias[o] = pk.v; }
  }
}

// ------- bucket base scan (nb <= 512, one block) + offs[N] = E -------
__global__ __launch_bounds__(512)
void bucket_scan(const int* __restrict__ bcnt, int* __restrict__ bbase,
                 int* __restrict__ offs_N, int nb, int E) {
  __shared__ int sm[512];
  const int t = threadIdx.x;
  int v = (t < nb) ? bcnt[t] : 0;
  sm[t] = v;
  __syncthreads();
  for (int off = 1; off < 512; off <<= 1) {
    int x = (t >= off) ? sm[t - off] : 0;
    __syncthreads();
    sm[t] += x;
    __syncthreads();
  }
  if (t < nb) bbase[t] = sm[t] - v;
  if (t == nb - 1) bbase[nb] = sm[t];
  if (t == 0) *offs_N = E;
}

// ------- edge pass 2: per-bucket exact CSR build in LDS, coalesced output -------
__global__ __launch_bounds__(256)
void bucket_scatter(const uint2* __restrict__ sd_arr, const uint4* __restrict__ bias_arr,
                    const int* __restrict__ bcnt, const int* __restrict__ bbase,
                    const int* __restrict__ ovf_cnt, const uint2* __restrict__ ovf_sd,
                    const uint4* __restrict__ ovf_bias,
                    int* __restrict__ csr_src, unsigned short* __restrict__ ebp,
                    int* __restrict__ offs, int N) {
  const int b = blockIdx.x;
  const int tid = threadIdx.x;
  const int dst0 = b << 7;
  const int ndst = min(128, N - dst0);
  const int base = bbase[b];
  const int cnt_true = bcnt[b];
  const int cnt_in = min(cnt_true, CAPB);
  __shared__ int lcnt[128], loff[128], wsum2[2];
  __shared__ int stage_src[CAPB];
  __shared__ uint4 stage_bias[CAPB];
  if (tid < 128) lcnt[tid] = 0;
  __syncthreads();
  const uint2* sd = sd_arr + (size_t)b * CAPB;
  const uint4* ba = bias_arr + (size_t)b * CAPB;
  for (int i = tid; i < cnt_in; i += 256) atomicAdd(&lcnt[(int)sd[i].y - dst0], 1);
  const int novf = *ovf_cnt;
  for (int j = tid; j < novf; j += 256) {
    uint2 s = ovf_sd[j];
    if ((int)(s.y >> 7) == b) atomicAdd(&lcnt[(int)s.y - dst0], 1);
  }
  __syncthreads();
  {
    const int lane = tid & 63;
    int v = (tid < 128) ? lcnt[tid] : 0;
    int inc = v;
#pragma unroll
    for (int off = 1; off < 64; off <<= 1) {
      int x = __shfl_up(inc, off);
      if (lane >= off) inc += x;
    }
    if (tid < 128 && lane == 63) wsum2[tid >> 6] = inc;
    __syncthreads();
    if (tid < 128) loff[tid] = inc - v + ((tid >= 64) ? wsum2[0] : 0);
  }
  __syncthreads();
  if (tid < ndst) offs[dst0 + tid] = base + loff[tid];
  if (tid < 128) lcnt[tid] = loff[tid];
  __syncthreads();
  for (int i = tid; i < cnt_in; i += 256) {
    uint2 s = sd[i];
    uint4 bi = ba[i];
    int p = atomicAdd(&lcnt[(int)s.y - dst0], 1);
    if (p < CAPB) { stage_src[p] = (int)s.x; stage_bias[p] = bi; }
    else { csr_src[base + p] = (int)s.x; *(uint4*)&ebp[(size_t)(base + p) * 8] = bi; }
  }
  for (int j = tid; j < novf; j += 256) {
    uint2 s = ovf_sd[j];
    if ((int)(s.y >> 7) != b) continue;
    uint4 bi = ovf_bias[j];
    int p = atomicAdd(&lcnt[(int)s.y - dst0], 1);
    if (p < CAPB) { stage_src[p] = (int)s.x; stage_bias[p] = bi; }
    else { csr_src[base + p] = (int)s.x; *(uint4*)&ebp[(size_t)(base + p) * 8] = bi; }
  }
  __syncthreads();
  const int nst = min(cnt_true, CAPB);
  for (int i = tid; i < nst; i += 256) {
    csr_src[base + i] = stage_src[i];
    *(uint4*)&ebp[(size_t)(base + i) * 8] = stage_bias[i];
  }
}

// ---------------- fused per-node attention aggregate (sequential ebp) ----------------
__global__ __launch_bounds__(256)
void node_agg(const int* __restrict__ csr_src, const int* __restrict__ offs,
              const unsigned short* __restrict__ qkv, const unsigned short* __restrict__ ebp,
              unsigned short* __restrict__ agg, int N) {
  const int wid = threadIdx.x >> 6, lane = threadIdx.x & 63;
  const int h = lane >> 3;
  const long n = (long)blockIdx.x * 4 + wid;
  if (n >= N) return;
  const int off = offs[n], end = offs[n + 1];
  const ushort2 kv2 = *(const ushort2*)&qkv[(size_t)n * 384 + 128 + lane * 2];
  const float k0 = bf2f(kv2.x), k1 = bf2f(kv2.y);
  float acc0 = 0.f, acc1 = 0.f, den = 0.f;
  int i = off;
  for (; i + 8 <= end; i += 8) {
    size_t bb[8];
#pragma unroll
    for (int u = 0; u < 8; ++u) bb[u] = (size_t)csr_src[i + u] * 384;
    ushort2 qv[8], vv[8];
#pragma unroll
    for (int u = 0; u < 8; ++u) qv[u] = *(const ushort2*)&qkv[bb[u] + lane * 2];
#pragma unroll
    for (int u = 0; u < 8; ++u) vv[u] = *(const ushort2*)&qkv[bb[u] + 256 + lane * 2];
    float ebv[8];
#pragma unroll
    for (int u = 0; u < 8; ++u) ebv[u] = bf2f(ebp[(size_t)(i + u) * 8 + h]);
    float p[8];
#pragma unroll
    for (int u = 0; u < 8; ++u) p[u] = bf2f(qv[u].x) * k0 + bf2f(qv[u].y) * k1;
#pragma unroll
    for (int u = 0; u < 8; ++u) {
      p[u] += __shfl_xor(p[u], 1);
      p[u] += __shfl_xor(p[u], 2);
      p[u] += __shfl_xor(p[u], 4);
    }
#pragma unroll
    for (int u = 0; u < 8; ++u) {
      const float ex = __expf(p[u] * 0.25f + ebv[u]);
      den += ex;
      acc0 += bf2f(vv[u].x) * ex;
      acc1 += bf2f(vv[u].y) * ex;
    }
  }
  for (; i + 4 <= end; i += 4) {
    size_t bb[4];
#pragma unroll
    for (int u = 0; u < 4; ++u) bb[u] = (size_t)csr_src[i + u] * 384;
    ushort2 qv[4], vv[4];
#pragma unroll
    for (int u = 0; u < 4; ++u) qv[u] = *(const ushort2*)&qkv[bb[u] + lane * 2];
#pragma unroll
    for (int u = 0; u < 4; ++u) vv[u] = *(const ushort2*)&qkv[bb[u] + 256 + lane * 2];
    float ebv[4];
#pragma unroll
    for (int u = 0; u < 4; ++u) ebv[u] = bf2f(ebp[(size_t)(i + u) * 8 + h]);
    float p[4];
#pragma unroll
    for (int u = 0; u < 4; ++u) p[u] = bf2f(qv[u].x) * k0 + bf2f(qv[u].y) * k1;
#pragma unroll
    for (int u = 0; u < 4; ++u) {
      p[u] += __shfl_xor(p[u], 1);
      p[u] += __shfl_xor(p[u], 2);
      p[u] += __shfl_xor(p[u], 4);
    }
#pragma unroll
    for (int u = 0; u < 4; ++u) {
      const float ex = __expf(p[u] * 0.25f + ebv[u]);
      den += ex;
      acc0 += bf2f(vv[u].x) * ex;
      acc1 += bf2f(vv[u].y) * ex;
    }
  }
  for (; i < end; ++i) {
    const size_t b0 = (size_t)csr_src[i] * 384;
    const ushort2 qa = *(const ushort2*)&qkv[b0 + lane * 2];
    const ushort2 va = *(const ushort2*)&qkv[b0 + 256 + lane * 2];
    float p = bf2f(qa.x) * k0 + bf2f(qa.y) * k1;
    p += __shfl_xor(p, 1);
    p += __shfl_xor(p, 2);
    p += __shfl_xor(p, 4);
    const float ex = __expf(p * 0.25f + bf2f(ebp[(size_t)i * 8 + h]));
    den += ex;
    acc0 += bf2f(va.x) * ex;
    acc1 += bf2f(va.y) * ex;
  }
  const float r = 1.f / fmaxf(den, 1e-8f);
  ushort2 o; o.x = f2bf(acc0 * r); o.y = f2bf(acc1 * r);
  *(ushort2*)&agg[(size_t)n * 128 + lane * 2] = o;
}

// ---------------- in-place LN(row of 512) -> exact GELU, bf16 ----------------
__global__ __launch_bounds__(256)
void ln_gelu512(unsigned short* __restrict__ hbuf, const float* __restrict__ g,
                const float* __restrict__ b, int Nr) {
  __shared__ float rs[4], rss[4];
  const long row = blockIdx.x;
  const int tid = threadIdx.x;
  ushort2 u = *(ushort2*)&hbuf[row * 512 + tid * 2];
  float v0 = bf2f(u.x), v1 = bf2f(u.y);
  float s = v0 + v1, ss = v0 * v0 + v1 * v1;
#pragma unroll
  for (int off = 32; off; off >>= 1) { s += __shfl_xor(s, off); ss += __shfl_xor(ss, off); }
  const int wid = tid >> 6, lane = tid & 63;
  if (lane == 0) { rs[wid] = s; rss[wid] = ss; }
  __syncthreads();
  s = rs[0] + rs[1] + rs[2] + rs[3];
  ss = rss[0] + rss[1] + rss[2] + rss[3];
  const float mu = s * (1.f / 512.f);
  const float inv = rsqrtf(ss * (1.f / 512.f) - mu * mu + LN_EPS);
  float t0 = (v0 - mu) * inv * g[tid * 2] + b[tid * 2];
  float t1 = (v1 - mu) * inv * g[tid * 2 + 1] + b[tid * 2 + 1];
  t0 = 0.5f * t0 * (1.f + erff(t0 * 0.70710678118654752f));
  t1 = 0.5f * t1 * (1.f + erff(t1 * 0.70710678118654752f));
  ushort2 o; o.x = f2bf(t0); o.y = f2bf(t1);
  *(ushort2*)&hbuf[row * 512 + tid * 2] = o;
}

extern "C" void kernel_launch(void* const* d_in, const int* in_sizes, int n_in,
                              void* d_out, int out_size, void* d_ws, size_t ws_size,
                              hipStream_t stream) {
  const float* x   = (const float*)d_in[0];
  const int*   ei  = (const int*)d_in[1];
  const float* ea  = (const float*)d_in[2];
  const float* qW  = (const float*)d_in[3];
  const float* qbi = (const float*)d_in[4];
  const float* kW  = (const float*)d_in[5];
  const float* kbi = (const float*)d_in[6];
  const float* vW  = (const float*)d_in[7];
  const float* vbi = (const float*)d_in[8];
  const float* eW  = (const float*)d_in[9];
  const float* eb  = (const float*)d_in[10];
  const float* oW  = (const float*)d_in[11];
  const float* ob  = (const float*)d_in[12];
  const float* ln1_g = (const float*)d_in[13];
  const float* ln1_b = (const float*)d_in[14];
  const float* f1W = (const float*)d_in[15];
  const float* f1b = (const float*)d_in[16];
  const float* lnf_g = (const float*)d_in[17];
  const float* lnf_b = (const float*)d_in[18];
  const float* f2W = (const float*)d_in[19];
  const float* f2b = (const float*)d_in[20];
  const float* ln2_g = (const float*)d_in[21];
  const float* ln2_b = (const float*)d_in[22];
  float* out = (float*)d_out;

  const int N = in_sizes[0] / 128;
  const int E = in_sizes[1] / 2;
  const size_t NH = (size_t)N * 128;   // 6.4M floats
  const int NBUCK = (N + 127) >> 7;    // 128 dsts per bucket

  // workspace (float units), lifetime-overlapped (~110 MB):
  //  [0, .5NH)      xbf bf16 -> x1bf
  //  [.5NH, 2NH)    qkv bf16 [N][384]; hbuf bf16 [N][512] overlays [.5NH, 2.5NH) (FFN phase)
  //  [2NH, 2.5NH)   ebp bf16 [E][8] (dead before f1)
  //  [2.5NH, 3NH)   aggb bf16
  //  [3NH, ...)     sd_arr, bias_arr, csr_src, offs, bcnt, bbase, ovf, weights
  float* F = (float*)d_ws;
  unsigned short* xbf   = (unsigned short*)F;
  unsigned short* qkvb  = (unsigned short*)(F + NH / 2);
  unsigned short* ebp   = (unsigned short*)(F + 2 * NH);
  unsigned short* aggb  = (unsigned short*)(F + 2 * NH + NH / 2);
  unsigned short* x1bf  = xbf;
  unsigned short* hbufb = (unsigned short*)(F + NH / 2);
  int* ib        = (int*)(F + 3 * NH);
  uint2* sd_arr  = (uint2*)ib;                                   // NBUCK*CAPB uint2
  uint4* bias_arr = (uint4*)(ib + 2 * (size_t)NBUCK * CAPB);     // NBUCK*CAPB uint4
  int* csr_src   = ib + 6 * (size_t)NBUCK * CAPB;                // E
  int* offs      = csr_src + E;                                  // N+1 (pad to N+4)
  int* bcnt      = offs + N + 4;                                 // NBUCK (pad)
  int* bbase     = bcnt + ((NBUCK + 3) & ~3);                    // NBUCK+1 (pad)
  int* ovf_cnt   = bbase + ((NBUCK + 4) & ~3);                   // 4
  uint2* ovf_sd  = (uint2*)(ovf_cnt + 4);                        // 4096
  uint4* ovf_bias = (uint4*)(ovf_cnt + 4 + 8192);                // 4096
  unsigned short* wt = (unsigned short*)(ovf_cnt + 4 + 8192 + 16384);
  unsigned short* qkvWt = wt;            // 384x128
  unsigned short* oWt   = wt + 49152;    // 128x128
  unsigned short* f1Wt  = wt + 65536;    // 512x128
  unsigned short* f2Wt  = wt + 131072;   // 128x512
  float* qkvbias = (float*)(wt + 196608);

  dim3 blk(256);
  dim3 gqkv((N + 127) / 128, 3);
  dim3 g128((N + 127) / 128, 1);
  dim3 gf1((N + 127) / 128, 4);
  const int ge = (E + 255) / 256;
  const int gA = (int)((NH / 4 + 255) / 256);

  // front: to_bf16 + counter-zero + all weight prep in ONE launch
  front<<<dim3(gA + 1 + 193), blk, 0, stream>>>(x, xbf, (long)NH, bcnt, NBUCK, ovf_cnt, gA,
                                                qW, kW, vW, oW, f1W, f2W,
                                                qkvWt, oWt, f1Wt, f2Wt,
                                                qbi, kbi, vbi, qkvbias);

  // merged QKV projection -> qkv[N][384] bf16
  gemm_mfma<true><<<gqkv, blk, 0, stream>>>(xbf, qkvWt, qkvbias, qkvb, N, 128, 384);

  // edge phase: bin (bias fused) -> bucket scan -> per-bucket CSR build
  edge_bin<<<dim3(ge), blk, 0, stream>>>(ei, ea, eW, eb, bcnt, sd_arr, bias_arr,
                                         ovf_cnt, ovf_sd, ovf_bias, E);
  bucket_scan<<<dim3(1), dim3(512), 0, stream>>>(bcnt, bbase, offs + N, NBUCK, E);
  bucket_scatter<<<dim3(NBUCK), blk, 0, stream>>>(sd_arr, bias_arr, bcnt, bbase,
                                                  ovf_cnt, ovf_sd, ovf_bias,
                                                  csr_src, ebp, offs, N);

  // fused attention aggregate (one wave per node, static)
  node_agg<<<dim3((N + 3) / 4), blk, 0, stream>>>(csr_src, offs, qkvb, ebp, aggb, N);

  // output projection fused with residual LN1 -> x1bf (bf16 residual from xbf)
  gemm_ln<false, true, true><<<g128, blk, 0, stream>>>(aggb, oWt, ob, xbf,
                                                       ln1_g, ln1_b, nullptr, x1bf, N, 128);

  // FFN: f1 GEMM, LN+GELU, f2 + LN2 -> out
  gemm_mfma<true><<<gf1, blk, 0, stream>>>(x1bf, f1Wt, f1b, hbufb, N, 128, 512);
  ln_gelu512<<<dim3(N), blk, 0, stream>>>(hbufb, lnf_g, lnf_b, N);
  gemm_ln<true, false, true><<<g128, blk, 0, stream>>>(hbufb, f2Wt, f2b, x1bf,
                                                       ln2_g, ln2_b, out, nullptr, N, 512);
}

// Round 13
// 393.833 us; speedup vs baseline: 1.2872x; 1.2872x over previous
//
#include <hip/hip_runtime.h>
#include <math.h>

#define LN_EPS 1e-5f

typedef __attribute__((ext_vector_type(8))) __bf16 bf16x8;
typedef __attribute__((ext_vector_type(4))) float f32x4;

__device__ inline float bf2f(unsigned short u) {
  union { unsigned int i; float f; } x; x.i = ((unsigned int)u) << 16; return x.f;
}
__device__ inline unsigned short f2bf(float f) {
  union { float f; unsigned int i; } x; x.f = f;
  unsigned int r = (x.i + 0x7FFFu + ((x.i >> 16) & 1u)) >> 16;   // RNE
  return (unsigned short)r;
}
__device__ inline void gload_lds16(const void* g, void* l) {
  __builtin_amdgcn_global_load_lds((const __attribute__((address_space(1))) void*)g,
                                   (__attribute__((address_space(3))) void*)l, 16, 0, 0);
}

// ------- front: to_bf16 ∪ pos-zero ∪ all weight transposes + bias concat, one launch -------
__global__ __launch_bounds__(256)
void front(const float* __restrict__ x, unsigned short* __restrict__ xbf, long n,
           int* __restrict__ pos, int N, int gA, int gZ,
           const float* qW, const float* kW, const float* vW, const float* oW,
           const float* f1W, const float* f2W,
           unsigned short* qkvWt, unsigned short* oWt,
           unsigned short* f1Wt, unsigned short* f2Wt,
           const float* qb, const float* kb, const float* vb, float* qkvbias) {
  const int b = blockIdx.x;
  const int tid = threadIdx.x;
  if (b < gA) {                       // f32 -> bf16
    long i = ((long)b * 256 + tid) * 4;
    if (i >= n) return;
    float4 v = *(const float4*)&x[i];
    ushort4 o = { f2bf(v.x), f2bf(v.y), f2bf(v.z), f2bf(v.w) };
    *(ushort4*)&xbf[i] = o;
    return;
  }
  if (b < gA + gZ) {                  // zero pos[N]
    int base = (b - gA) * 1024 + tid * 4;
    if (base + 3 < N) *(int4*)(pos + base) = make_int4(0, 0, 0, 0);
    else for (int j = 0; j < 4; ++j) if (base + j < N) pos[base + j] = 0;
    return;
  }
  const int t = b - gA - gZ;          // weight prep tiles
  if (t == 192) {
    int i = tid;
    if (i < 128) { qkvbias[i] = qb[i]; qkvbias[128 + i] = kb[i]; }
    else if (i < 256) qkvbias[256 + (i - 128)] = vb[i - 128];
    return;
  }
  const float* W; unsigned short* Wt; int K, M, lt;
  if (t < 64)       { K = 128; M = 128; lt = t & 15;
    if (t < 16)      { W = qW; Wt = qkvWt; }
    else if (t < 32) { W = kW; Wt = qkvWt + 16384; }
    else if (t < 48) { W = vW; Wt = qkvWt + 32768; }
    else             { W = oW; Wt = oWt; } }
  else if (t < 128) { K = 128; M = 512; lt = t - 64; W = f1W; Wt = f1Wt; }
  else              { K = 512; M = 128; lt = t - 128; W = f2W; Wt = f2Wt; }
  const int ktiles = K >> 5;
  const int k0 = (lt % ktiles) * 32, m0 = (lt / ktiles) * 32;
  __shared__ float tb[32][33];
  const int tx = tid & 31, ty = tid >> 5;  // 32 x 8
#pragma unroll
  for (int i = 0; i < 32; i += 8)
    tb[ty + i][tx] = W[(size_t)(k0 + ty + i) * M + m0 + tx];
  __syncthreads();
#pragma unroll
  for (int i = 0; i < 32; i += 8)
    Wt[(size_t)(m0 + ty + i) * K + k0 + tx] = f2bf(tb[tx][ty + i]);
}

// ------- bf16 MFMA GEMM: C[N,M] = A[N,K] @ Wt[M,K]^T + bias; STATS -> row LN partials -------
template<bool OBF, bool STATS>
__global__ __launch_bounds__(256)
void gemm_mfma(const unsigned short* __restrict__ A, const unsigned short* __restrict__ Wt,
               const float* __restrict__ bias, void* __restrict__ Cout,
               float2* __restrict__ rpart, int Np, int Nr, int K, int M) {
  __shared__ __align__(16) unsigned short As[128 * 64];
  __shared__ __align__(16) unsigned short Bs[128 * 64];
  __shared__ float spls[128][2], splss[128][2];
  const int tid = threadIdx.x;
  const int bm = blockIdx.x * 128, bn = blockIdx.y * 128;
  const int lane = tid & 63;
  const int wr = (tid >> 6) >> 1, wc = (tid >> 6) & 1;
  f32x4 acc[4][4] = {};
  const int nkt = K >> 6;
  for (int kt = 0; kt < nkt; ++kt) {
#pragma unroll
    for (int i = 0; i < 4; ++i) {
      int c = tid + i * 256;
      int row = c >> 3;
      int j = (c & 7) ^ (row & 7);
      int ar = bm + row; ar = ar < Nr ? ar : Nr - 1;
      gload_lds16(A + (size_t)ar * K + kt * 64 + j * 8, As + (size_t)c * 8);
      gload_lds16(Wt + (size_t)(bn + row) * K + kt * 64 + j * 8, Bs + (size_t)c * 8);
    }
    __syncthreads();
#pragma unroll
    for (int ks = 0; ks < 2; ++ks) {
      bf16x8 af[4], bfr[4];
#pragma unroll
      for (int f = 0; f < 4; ++f) {
        int rowa = wr * 64 + f * 16 + (lane & 15);
        int ja = (ks * 4 + (lane >> 4)) ^ (rowa & 7);
        af[f] = *(const bf16x8*)(As + rowa * 64 + ja * 8);
        int rowb = wc * 64 + f * 16 + (lane & 15);
        int jb = (ks * 4 + (lane >> 4)) ^ (rowb & 7);
        bfr[f] = *(const bf16x8*)(Bs + rowb * 64 + jb * 8);
      }
#pragma unroll
      for (int fr = 0; fr < 4; ++fr)
#pragma unroll
        for (int fc = 0; fc < 4; ++fc)
          acc[fr][fc] = __builtin_amdgcn_mfma_f32_16x16x32_bf16(af[fr], bfr[fc], acc[fr][fc], 0, 0, 0);
    }
    __syncthreads();
  }
#pragma unroll
  for (int fr = 0; fr < 4; ++fr) {
#pragma unroll
    for (int j = 0; j < 4; ++j) {
      const int rl = wr * 64 + fr * 16 + (lane >> 4) * 4 + j;
      const int row = bm + rl;
      float s = 0.f, ss = 0.f;
#pragma unroll
      for (int fc = 0; fc < 4; ++fc) {
        int col = bn + wc * 64 + fc * 16 + (lane & 15);
        float v = acc[fr][fc][j] + bias[col];
        if (row < Nr) {
          if (OBF) ((unsigned short*)Cout)[(size_t)row * M + col] = f2bf(v);
          else     ((float*)Cout)[(size_t)row * M + col] = v;
        }
        s += v; ss += v * v;
      }
      if (STATS) {
        s += __shfl_xor(s, 1); ss += __shfl_xor(ss, 1);
        s += __shfl_xor(s, 2); ss += __shfl_xor(ss, 2);
        s += __shfl_xor(s, 4); ss += __shfl_xor(ss, 4);
        s += __shfl_xor(s, 8); ss += __shfl_xor(ss, 8);
        if ((lane & 15) == 0) { spls[rl][wc] = s; splss[rl][wc] = ss; }
      }
    }
  }
  if (STATS) {
    __syncthreads();
    if (tid < 128) {
      int row = bm + tid;
      if (row < Nr)
        rpart[(size_t)blockIdx.y * Np + row] =
            make_float2(spls[tid][0] + spls[tid][1], splss[tid][0] + splss[tid][1]);
    }
  }
}

// ------- bf16 MFMA GEMM (M=128) fused with y = LN(res + A@Wt^T + bias) -------
// ALN: A is pre-LN hbuf; apply LN(lnf)+GELU inline on A fragments using rpart stats
template<bool WF32, bool WBF, bool RESBF, bool ALN>
__global__ __launch_bounds__(256)
void gemm_ln(const unsigned short* __restrict__ A, const unsigned short* __restrict__ Wt,
             const float* __restrict__ bias, const void* __restrict__ res,
             const float* __restrict__ g, const float* __restrict__ b,
             float* __restrict__ y, unsigned short* __restrict__ ybf,
             const float2* __restrict__ rpart, int Np,
             const float* __restrict__ ag, const float* __restrict__ ab,
             int Nr, int K) {
  __shared__ __align__(16) unsigned short As[128 * 64];
  __shared__ __align__(16) unsigned short Bs[128 * 64];
  __shared__ float pls[128][2], plss[128][2];
  __shared__ float muv[128], invv[128];
  __shared__ float aglds[512], ablds[512];
  const int tid = threadIdx.x;
  const int bm = blockIdx.x * 128;
  const int lane = tid & 63;
  const int wr = (tid >> 6) >> 1, wc = (tid >> 6) & 1;
  if (ALN) {
    if (tid < 128) {
      int row = bm + tid; row = row < Nr ? row : Nr - 1;
      float2 p0 = rpart[row], p1 = rpart[(size_t)Np + row];
      float2 p2 = rpart[2 * (size_t)Np + row], p3 = rpart[3 * (size_t)Np + row];
      float s = (p0.x + p1.x) + (p2.x + p3.x);
      float ss = (p0.y + p1.y) + (p2.y + p3.y);
      float mu = s * (1.f / 512.f);
      muv[tid] = mu;
      invv[tid] = rsqrtf(ss * (1.f / 512.f) - mu * mu + LN_EPS);
    }
    aglds[tid] = ag[tid]; aglds[256 + tid] = ag[256 + tid];
    ablds[tid] = ab[tid]; ablds[256 + tid] = ab[256 + tid];
    __syncthreads();
  }
  f32x4 acc[4][4] = {};
  const int nkt = K >> 6;
  for (int kt = 0; kt < nkt; ++kt) {
#pragma unroll
    for (int i = 0; i < 4; ++i) {
      int c = tid + i * 256;
      int row = c >> 3;
      int j = (c & 7) ^ (row & 7);
      int ar = bm + row; ar = ar < Nr ? ar : Nr - 1;
      gload_lds16(A + (size_t)ar * K + kt * 64 + j * 8, As + (size_t)c * 8);
      gload_lds16(Wt + (size_t)row * K + kt * 64 + j * 8, Bs + (size_t)c * 8);
    }
    __syncthreads();
#pragma unroll
    for (int ks = 0; ks < 2; ++ks) {
      bf16x8 af[4], bfr[4];
#pragma unroll
      for (int f = 0; f < 4; ++f) {
        int rowa = wr * 64 + f * 16 + (lane & 15);
        int ja = (ks * 4 + (lane >> 4)) ^ (rowa & 7);
        af[f] = *(const bf16x8*)(As + rowa * 64 + ja * 8);
        int rowb = wc * 64 + f * 16 + (lane & 15);
        int jb = (ks * 4 + (lane >> 4)) ^ (rowb & 7);
        bfr[f] = *(const bf16x8*)(Bs + rowb * 64 + jb * 8);
      }
      if (ALN) {
        const int colbase = kt * 64 + (ks * 4 + (lane >> 4)) * 8;
#pragma unroll
        for (int f = 0; f < 4; ++f) {
          const int rowa = wr * 64 + f * 16 + (lane & 15);
          const float mu = muv[rowa], inv = invv[rowa];
          union { bf16x8 v; unsigned short us[8]; } ua;
          ua.v = af[f];
#pragma unroll
          for (int el = 0; el < 8; ++el) {
            float t = (bf2f(ua.us[el]) - mu) * inv * aglds[colbase + el] + ablds[colbase + el];
            t = 0.5f * t * (1.f + erff(t * 0.70710678118654752f));
            ua.us[el] = f2bf(t);
          }
          af[f] = ua.v;
        }
      }
#pragma unroll
      for (int fr = 0; fr < 4; ++fr)
#pragma unroll
        for (int fc = 0; fc < 4; ++fc)
          acc[fr][fc] = __builtin_amdgcn_mfma_f32_16x16x32_bf16(af[fr], bfr[fc], acc[fr][fc], 0, 0, 0);
    }
    __syncthreads();
  }
#pragma unroll
  for (int fr = 0; fr < 4; ++fr) {
#pragma unroll
    for (int j = 0; j < 4; ++j) {
      const int rl = wr * 64 + fr * 16 + (lane >> 4) * 4 + j;
      const int row = bm + rl;
      const int rowc = row < Nr ? row : Nr - 1;
      float s = 0.f, ss = 0.f;
#pragma unroll
      for (int fc = 0; fc < 4; ++fc) {
        int col = wc * 64 + fc * 16 + (lane & 15);
        float rv = RESBF ? bf2f(((const unsigned short*)res)[(size_t)rowc * 128 + col])
                         : ((const float*)res)[(size_t)rowc * 128 + col];
        float val = acc[fr][fc][j] + bias[col] + rv;
        acc[fr][fc][j] = val;
        s += val; ss += val * val;
      }
      s += __shfl_xor(s, 1); ss += __shfl_xor(ss, 1);
      s += __shfl_xor(s, 2); ss += __shfl_xor(ss, 2);
      s += __shfl_xor(s, 4); ss += __shfl_xor(ss, 4);
      s += __shfl_xor(s, 8); ss += __shfl_xor(ss, 8);
      if ((lane & 15) == 0) { pls[rl][wc] = s; plss[rl][wc] = ss; }
    }
  }
  __syncthreads();
#pragma unroll
  for (int fr = 0; fr < 4; ++fr) {
#pragma unroll
    for (int j = 0; j < 4; ++j) {
      const int rl = wr * 64 + fr * 16 + (lane >> 4) * 4 + j;
      const int row = bm + rl;
      if (row >= Nr) continue;
      const float S = pls[rl][0] + pls[rl][1];
      const float SS = plss[rl][0] + plss[rl][1];
      const float mu = S * (1.f / 128.f);
      const float inv = rsqrtf(SS * (1.f / 128.f) - mu * mu + LN_EPS);
#pragma unroll
      for (int fc = 0; fc < 4; ++fc) {
        int col = wc * 64 + fc * 16 + (lane & 15);
        float o = (acc[fr][fc][j] - mu) * inv * g[col] + b[col];
        if (WF32) y[(size_t)row * 128 + col] = o;
        if (WBF)  ybf[(size_t)row * 128 + col] = f2bf(o);
      }
    }
  }
}

// ---------------- CSR build ----------------
__global__ __launch_bounds__(256)
void edge_hist(const int* __restrict__ ei, int* __restrict__ deg, int E) {
  int e = blockIdx.x * 256 + threadIdx.x;
  if (e < E) atomicAdd(&deg[ei[E + e]], 1);
}

__global__ __launch_bounds__(256)
void deg_block_sum(const int* __restrict__ deg, int* __restrict__ bsum, int N) {
  const int t = threadIdx.x;
  const int beg = blockIdx.x * 2048 + t * 8;
  int s = 0;
#pragma unroll
  for (int j = 0; j < 8; ++j) { int i = beg + j; if (i < N) s += deg[i]; }
#pragma unroll
  for (int off = 32; off; off >>= 1) s += __shfl_xor(s, off);
  __shared__ int ws[4];
  if ((t & 63) == 0) ws[t >> 6] = s;
  __syncthreads();
  if (t == 0) bsum[blockIdx.x] = ws[0] + ws[1] + ws[2] + ws[3];
}

__global__ __launch_bounds__(64)
void scan_bsum(int* __restrict__ bsum, int* __restrict__ offs_last, int nb) {
  const int t = threadIdx.x;
  int v = (t < nb) ? bsum[t] : 0;
  int inc = v;
#pragma unroll
  for (int off = 1; off < 64; off <<= 1) {
    int x = __shfl_up(inc, off);
    if (t >= off) inc += x;
  }
  if (t < nb) bsum[t] = inc - v;
  if (t == 63) *offs_last = inc;
}

__global__ __launch_bounds__(256)
void deg_scan_write(const int* __restrict__ deg, const int* __restrict__ bsum,
                    int* __restrict__ offs, int* __restrict__ pos, int N) {
  const int t = threadIdx.x;
  const int beg = blockIdx.x * 2048 + t * 8;
  int loc[8]; int T = 0;
#pragma unroll
  for (int j = 0; j < 8; ++j) { int i = beg + j; loc[j] = (i < N) ? deg[i] : 0; T += loc[j]; }
  int inc = T;
#pragma unroll
  for (int off = 1; off < 64; off <<= 1) {
    int x = __shfl_up(inc, off);
    if ((t & 63) >= off) inc += x;
  }
  __shared__ int ws[4];
  if ((t & 63) == 63) ws[t >> 6] = inc;
  __syncthreads();
  const int wid = t >> 6;
  int wbase = 0;
  for (int w = 0; w < wid; ++w) wbase += ws[w];
  int base = bsum[blockIdx.x] + wbase + inc - T;
#pragma unroll
  for (int j = 0; j < 8; ++j) {
    int i = beg + j;
    if (i < N) { offs[i] = base; pos[i] = base; base += loc[j]; }
  }
}

// scatter fused with edge-bias: ebp[p][h] = bf16( ea[e,:]@eW[:,h] + eb[h] )
__global__ __launch_bounds__(256)
void edge_scatter_bias(const int* __restrict__ ei, int* __restrict__ pos,
                       const float* __restrict__ ea, const float* __restrict__ eW,
                       const float* __restrict__ eb, int* __restrict__ csr_src,
                       unsigned short* __restrict__ ebp, int E) {
  __shared__ float ews[256];
  __shared__ float ebs[8];
  const int tid = threadIdx.x;
  if (tid < 256) ews[tid] = eW[tid];
  if (tid < 8) ebs[tid] = eb[tid];
  __syncthreads();
  int e = blockIdx.x * 256 + tid;
  if (e >= E) return;
  float bias[8];
#pragma unroll
  for (int h = 0; h < 8; ++h) bias[h] = ebs[h];
#pragma unroll
  for (int i4 = 0; i4 < 8; ++i4) {
    float4 a = *(const float4*)&ea[(size_t)e * 32 + i4 * 4];
    float av[4] = {a.x, a.y, a.z, a.w};
#pragma unroll
    for (int j = 0; j < 4; ++j)
#pragma unroll
      for (int h = 0; h < 8; ++h) bias[h] += av[j] * ews[(i4 * 4 + j) * 8 + h];
  }
  int d = ei[E + e];
  int p = atomicAdd(&pos[d], 1);
  csr_src[p] = ei[e];
  union { unsigned short us[8]; uint4 v; } pk;
#pragma unroll
  for (int h = 0; h < 8; ++h) pk.us[h] = f2bf(bias[h]);
  *(uint4*)&ebp[(size_t)p * 8] = pk.v;
}

// ---------------- fused per-node attention aggregate (sequential ebp) ----------------
__global__ __launch_bounds__(256)
void node_agg(const int* __restrict__ csr_src, const int* __restrict__ offs,
              const unsigned short* __restrict__ qkv, const unsigned short* __restrict__ ebp,
              unsigned short* __restrict__ agg, int N) {
  const int wid = threadIdx.x >> 6, lane = threadIdx.x & 63;
  const int h = lane >> 3;
  const long n = (long)blockIdx.x * 4 + wid;
  if (n >= N) return;
  const int off = offs[n], end = offs[n + 1];
  const ushort2 kv2 = *(const ushort2*)&qkv[(size_t)n * 384 + 128 + lane * 2];
  const float k0 = bf2f(kv2.x), k1 = bf2f(kv2.y);
  float acc0 = 0.f, acc1 = 0.f, den = 0.f;
  int i = off;
  for (; i + 8 <= end; i += 8) {
    size_t bb[8];
#pragma unroll
    for (int u = 0; u < 8; ++u) bb[u] = (size_t)csr_src[i + u] * 384;
    ushort2 qv[8], vv[8];
#pragma unroll
    for (int u = 0; u < 8; ++u) qv[u] = *(const ushort2*)&qkv[bb[u] + lane * 2];
#pragma unroll
    for (int u = 0; u < 8; ++u) vv[u] = *(const ushort2*)&qkv[bb[u] + 256 + lane * 2];
    float ebv[8];
#pragma unroll
    for (int u = 0; u < 8; ++u) ebv[u] = bf2f(ebp[(size_t)(i + u) * 8 + h]);
    float p[8];
#pragma unroll
    for (int u = 0; u < 8; ++u) p[u] = bf2f(qv[u].x) * k0 + bf2f(qv[u].y) * k1;
#pragma unroll
    for (int u = 0; u < 8; ++u) {
      p[u] += __shfl_xor(p[u], 1);
      p[u] += __shfl_xor(p[u], 2);
      p[u] += __shfl_xor(p[u], 4);
    }
#pragma unroll
    for (int u = 0; u < 8; ++u) {
      const float ex = __expf(p[u] * 0.25f + ebv[u]);
      den += ex;
      acc0 += bf2f(vv[u].x) * ex;
      acc1 += bf2f(vv[u].y) * ex;
    }
  }
  for (; i + 4 <= end; i += 4) {
    size_t bb[4];
#pragma unroll
    for (int u = 0; u < 4; ++u) bb[u] = (size_t)csr_src[i + u] * 384;
    ushort2 qv[4], vv[4];
#pragma unroll
    for (int u = 0; u < 4; ++u) qv[u] = *(const ushort2*)&qkv[bb[u] + lane * 2];
#pragma unroll
    for (int u = 0; u < 4; ++u) vv[u] = *(const ushort2*)&qkv[bb[u] + 256 + lane * 2];
    float ebv[4];
#pragma unroll
    for (int u = 0; u < 4; ++u) ebv[u] = bf2f(ebp[(size_t)(i + u) * 8 + h]);
    float p[4];
#pragma unroll
    for (int u = 0; u < 4; ++u) p[u] = bf2f(qv[u].x) * k0 + bf2f(qv[u].y) * k1;
#pragma unroll
    for (int u = 0; u < 4; ++u) {
      p[u] += __shfl_xor(p[u], 1);
      p[u] += __shfl_xor(p[u], 2);
      p[u] += __shfl_xor(p[u], 4);
    }
#pragma unroll
    for (int u = 0; u < 4; ++u) {
      const float ex = __expf(p[u] * 0.25f + ebv[u]);
      den += ex;
      acc0 += bf2f(vv[u].x) * ex;
      acc1 += bf2f(vv[u].y) * ex;
    }
  }
  for (; i < end; ++i) {
    const size_t b0 = (size_t)csr_src[i] * 384;
    const ushort2 qa = *(const ushort2*)&qkv[b0 + lane * 2];
    const ushort2 va = *(const ushort2*)&qkv[b0 + 256 + lane * 2];
    float p = bf2f(qa.x) * k0 + bf2f(qa.y) * k1;
    p += __shfl_xor(p, 1);
    p += __shfl_xor(p, 2);
    p += __shfl_xor(p, 4);
    const float ex = __expf(p * 0.25f + bf2f(ebp[(size_t)i * 8 + h]));
    den += ex;
    acc0 += bf2f(va.x) * ex;
    acc1 += bf2f(va.y) * ex;
  }
  const float r = 1.f / fmaxf(den, 1e-8f);
  ushort2 o; o.x = f2bf(acc0 * r); o.y = f2bf(acc1 * r);
  *(ushort2*)&agg[(size_t)n * 128 + lane * 2] = o;
}

extern "C" void kernel_launch(void* const* d_in, const int* in_sizes, int n_in,
                              void* d_out, int out_size, void* d_ws, size_t ws_size,
                              hipStream_t stream) {
  const float* x   = (const float*)d_in[0];
  const int*   ei  = (const int*)d_in[1];
  const float* ea  = (const float*)d_in[2];
  const float* qW  = (const float*)d_in[3];
  const float* qbi = (const float*)d_in[4];
  const float* kW  = (const float*)d_in[5];
  const float* kbi = (const float*)d_in[6];
  const float* vW  = (const float*)d_in[7];
  const float* vbi = (const float*)d_in[8];
  const float* eW  = (const float*)d_in[9];
  const float* eb  = (const float*)d_in[10];
  const float* oW  = (const float*)d_in[11];
  const float* ob  = (const float*)d_in[12];
  const float* ln1_g = (const float*)d_in[13];
  const float* ln1_b = (const float*)d_in[14];
  const float* f1W = (const float*)d_in[15];
  const float* f1b = (const float*)d_in[16];
  const float* lnf_g = (const float*)d_in[17];
  const float* lnf_b = (const float*)d_in[18];
  const float* f2W = (const float*)d_in[19];
  const float* f2b = (const float*)d_in[20];
  const float* ln2_g = (const float*)d_in[21];
  const float* ln2_b = (const float*)d_in[22];
  float* out = (float*)d_out;

  const int N = in_sizes[0] / 128;
  const int E = in_sizes[1] / 2;
  const size_t NH = (size_t)N * 128;   // 6.4M floats

  // workspace (float units), lifetime-overlapped:
  //  [0, .5NH)      xbf bf16 -> x1bf
  //  [.5NH, 2.5NH)  qkv bf16 [N][384] + ebp bf16 [E][8] at [2NH,2.5NH);
  //                 hbuf bf16 [N][512] overlays [.5NH, 2.5NH) in FFN phase (qkv+ebp dead)
  //  [2.5NH, 3NH)   aggb bf16
  //  [3NH, ...)     rpart f32x2 [4][N]
  //  [4NH, ...)     ints: csr_src E, offs N+1, pos N, bsum; then bf16 weights + bias
  float* F = (float*)d_ws;
  unsigned short* xbf   = (unsigned short*)F;
  unsigned short* qkvb  = (unsigned short*)(F + NH / 2);
  unsigned short* ebp   = (unsigned short*)(F + 2 * NH);
  unsigned short* aggb  = (unsigned short*)(F + 2 * NH + NH / 2);
  unsigned short* x1bf  = xbf;
  unsigned short* hbufb = (unsigned short*)(F + NH / 2);
  float2* rpart = (float2*)(F + 3 * NH);          // 4*N float2
  int* ib      = (int*)(F + 4 * NH);
  int* csr_src = ib;
  int* offs    = ib + E;
  int* pos     = ib + E + N + 1;
  int* bsum    = ib + E + 2 * N + 1;
  unsigned short* wt = (unsigned short*)(ib + E + 2 * N + 128);
  unsigned short* qkvWt = wt;            // 384x128
  unsigned short* oWt   = wt + 49152;    // 128x128
  unsigned short* f1Wt  = wt + 65536;    // 512x128
  unsigned short* f2Wt  = wt + 131072;   // 128x512
  float* qkvbias = (float*)(wt + 196608);

  dim3 blk(256);
  dim3 gqkv((N + 127) / 128, 3);
  dim3 g128((N + 127) / 128, 1);
  dim3 gf1((N + 127) / 128, 4);
  const int nb = (N + 2047) / 2048;
  const int ge = (E + 255) / 256;
  const int gA = (int)((NH / 4 + 255) / 256);
  const int gZ = (N + 1023) / 1024;

  // front: to_bf16 + pos-zero + all weight prep in ONE launch
  front<<<dim3(gA + gZ + 193), blk, 0, stream>>>(x, xbf, (long)NH, pos, N, gA, gZ,
                                                 qW, kW, vW, oW, f1W, f2W,
                                                 qkvWt, oWt, f1Wt, f2Wt,
                                                 qbi, kbi, vbi, qkvbias);

  // merged QKV projection -> qkv[N][384] bf16
  gemm_mfma<true, false><<<gqkv, blk, 0, stream>>>(xbf, qkvWt, qkvbias, qkvb,
                                                   nullptr, 0, N, 128, 384);

  // CSR by dst: hist -> scans -> fused bias+scatter
  edge_hist<<<dim3(ge), blk, 0, stream>>>(ei, pos, E);
  deg_block_sum<<<dim3(nb), blk, 0, stream>>>(pos, bsum, N);
  scan_bsum<<<dim3(1), dim3(64), 0, stream>>>(bsum, offs + N, nb);
  deg_scan_write<<<dim3(nb), blk, 0, stream>>>(pos, bsum, offs, pos, N);
  edge_scatter_bias<<<dim3(ge), blk, 0, stream>>>(ei, pos, ea, eW, eb, csr_src, ebp, E);

  // fused attention aggregate (one wave per node, static)
  node_agg<<<dim3((N + 3) / 4), blk, 0, stream>>>(csr_src, offs, qkvb, ebp, aggb, N);

  // output projection fused with residual LN1 -> x1bf (bf16 residual from xbf)
  gemm_ln<false, true, true, false><<<g128, blk, 0, stream>>>(
      aggb, oWt, ob, xbf, ln1_g, ln1_b, nullptr, x1bf,
      nullptr, 0, nullptr, nullptr, N, 128);

  // FFN: f1 GEMM (pre-LN hbuf + row stats), then f2 with inline LN(lnf)+GELU + LN2 -> out
  gemm_mfma<true, true><<<gf1, blk, 0, stream>>>(x1bf, f1Wt, f1b, hbufb,
                                                 (float2*)rpart, N, N, 128, 512);
  gemm_ln<true, false, true, true><<<g128, blk, 0, stream>>>(
      hbufb, f2Wt, f2b, x1bf, ln2_g, ln2_b, out, nullptr,
      (const float2*)rpart, N, lnf_g, lnf_b, N, 512);
}

// Round 14
// 299.835 us; speedup vs baseline: 1.6908x; 1.3135x over previous
//
#include <hip/hip_runtime.h>
#include <math.h>

#define LN_EPS 1e-5f

typedef __attribute__((ext_vector_type(8))) __bf16 bf16x8;
typedef __attribute__((ext_vector_type(4))) float f32x4;

__device__ inline float bf2f(unsigned short u) {
  union { unsigned int i; float f; } x; x.i = ((unsigned int)u) << 16; return x.f;
}
__device__ inline unsigned short f2bf(float f) {
  union { float f; unsigned int i; } x; x.f = f;
  unsigned int r = (x.i + 0x7FFFu + ((x.i >> 16) & 1u)) >> 16;   // RNE
  return (unsigned short)r;
}
__device__ inline void gload_lds16(const void* g, void* l) {
  __builtin_amdgcn_global_load_lds((const __attribute__((address_space(1))) void*)g,
                                   (__attribute__((address_space(3))) void*)l, 16, 0, 0);
}

// ------- front: to_bf16 ∪ pos-zero ∪ all weight transposes + bias concat, one launch -------
__global__ __launch_bounds__(256)
void front(const float* __restrict__ x, unsigned short* __restrict__ xbf, long n,
           int* __restrict__ pos, int N, int gA, int gZ,
           const float* qW, const float* kW, const float* vW, const float* oW,
           const float* f1W, const float* f2W,
           unsigned short* qkvWt, unsigned short* oWt,
           unsigned short* f1Wt, unsigned short* f2Wt,
           const float* qb, const float* kb, const float* vb, float* qkvbias) {
  const int b = blockIdx.x;
  const int tid = threadIdx.x;
  if (b < gA) {                       // f32 -> bf16
    long i = ((long)b * 256 + tid) * 4;
    if (i >= n) return;
    float4 v = *(const float4*)&x[i];
    ushort4 o = { f2bf(v.x), f2bf(v.y), f2bf(v.z), f2bf(v.w) };
    *(ushort4*)&xbf[i] = o;
    return;
  }
  if (b < gA + gZ) {                  // zero pos[N]
    int base = (b - gA) * 1024 + tid * 4;
    if (base + 3 < N) *(int4*)(pos + base) = make_int4(0, 0, 0, 0);
    else for (int j = 0; j < 4; ++j) if (base + j < N) pos[base + j] = 0;
    return;
  }
  const int t = b - gA - gZ;          // weight prep tiles
  if (t == 192) {
    int i = tid;
    if (i < 128) { qkvbias[i] = qb[i]; qkvbias[128 + i] = kb[i]; }
    else if (i < 256) qkvbias[256 + (i - 128)] = vb[i - 128];
    return;
  }
  const float* W; unsigned short* Wt; int K, M, lt;
  if (t < 64)       { K = 128; M = 128; lt = t & 15;
    if (t < 16)      { W = qW; Wt = qkvWt; }
    else if (t < 32) { W = kW; Wt = qkvWt + 16384; }
    else if (t < 48) { W = vW; Wt = qkvWt + 32768; }
    else             { W = oW; Wt = oWt; } }
  else if (t < 128) { K = 128; M = 512; lt = t - 64; W = f1W; Wt = f1Wt; }
  else              { K = 512; M = 128; lt = t - 128; W = f2W; Wt = f2Wt; }
  const int ktiles = K >> 5;
  const int k0 = (lt % ktiles) * 32, m0 = (lt / ktiles) * 32;
  __shared__ float tb[32][33];
  const int tx = tid & 31, ty = tid >> 5;  // 32 x 8
#pragma unroll
  for (int i = 0; i < 32; i += 8)
    tb[ty + i][tx] = W[(size_t)(k0 + ty + i) * M + m0 + tx];
  __syncthreads();
#pragma unroll
  for (int i = 0; i < 32; i += 8)
    Wt[(size_t)(m0 + ty + i) * K + k0 + tx] = f2bf(tb[tx][ty + i]);
}

// ---------------- bf16 MFMA GEMM: C[N,M] = A[N,K] @ Wt[M,K]^T + bias ----------------
template<bool OBF>
__global__ __launch_bounds__(256)
void gemm_mfma(const unsigned short* __restrict__ A, const unsigned short* __restrict__ Wt,
               const float* __restrict__ bias, void* __restrict__ Cout,
               int Nr, int K, int M) {
  __shared__ __align__(16) unsigned short As[128 * 64];
  __shared__ __align__(16) unsigned short Bs[128 * 64];
  const int tid = threadIdx.x;
  const int bm = blockIdx.x * 128, bn = blockIdx.y * 128;
  const int lane = tid & 63;
  const int wr = (tid >> 6) >> 1, wc = (tid >> 6) & 1;
  f32x4 acc[4][4] = {};
  const int nkt = K >> 6;
  for (int kt = 0; kt < nkt; ++kt) {
#pragma unroll
    for (int i = 0; i < 4; ++i) {
      int c = tid + i * 256;
      int row = c >> 3;
      int j = (c & 7) ^ (row & 7);
      int ar = bm + row; ar = ar < Nr ? ar : Nr - 1;
      gload_lds16(A + (size_t)ar * K + kt * 64 + j * 8, As + (size_t)c * 8);
      gload_lds16(Wt + (size_t)(bn + row) * K + kt * 64 + j * 8, Bs + (size_t)c * 8);
    }
    __syncthreads();
#pragma unroll
    for (int ks = 0; ks < 2; ++ks) {
      bf16x8 af[4], bfr[4];
#pragma unroll
      for (int f = 0; f < 4; ++f) {
        int rowa = wr * 64 + f * 16 + (lane & 15);
        int ja = (ks * 4 + (lane >> 4)) ^ (rowa & 7);
        af[f] = *(const bf16x8*)(As + rowa * 64 + ja * 8);
        int rowb = wc * 64 + f * 16 + (lane & 15);
        int jb = (ks * 4 + (lane >> 4)) ^ (rowb & 7);
        bfr[f] = *(const bf16x8*)(Bs + rowb * 64 + jb * 8);
      }
#pragma unroll
      for (int fr = 0; fr < 4; ++fr)
#pragma unroll
        for (int fc = 0; fc < 4; ++fc)
          acc[fr][fc] = __builtin_amdgcn_mfma_f32_16x16x32_bf16(af[fr], bfr[fc], acc[fr][fc], 0, 0, 0);
    }
    __syncthreads();
  }
#pragma unroll
  for (int fr = 0; fr < 4; ++fr) {
#pragma unroll
    for (int j = 0; j < 4; ++j) {
      int row = bm + wr * 64 + fr * 16 + (lane >> 4) * 4 + j;
      if (row < Nr) {
#pragma unroll
        for (int fc = 0; fc < 4; ++fc) {
          int col = bn + wc * 64 + fc * 16 + (lane & 15);
          float v = acc[fr][fc][j] + bias[col];
          if (OBF) ((unsigned short*)Cout)[(size_t)row * M + col] = f2bf(v);
          else     ((float*)Cout)[(size_t)row * M + col] = v;
        }
      }
    }
  }
}

// ------- bf16 MFMA GEMM (M=128) fused with y = LN(res + A@Wt^T + bias) -------
template<bool WF32, bool WBF, bool RESBF>
__global__ __launch_bounds__(256)
void gemm_ln(const unsigned short* __restrict__ A, const unsigned short* __restrict__ Wt,
             const float* __restrict__ bias, const void* __restrict__ res,
             const float* __restrict__ g, const float* __restrict__ b,
             float* __restrict__ y, unsigned short* __restrict__ ybf, int Nr, int K) {
  __shared__ __align__(16) unsigned short As[128 * 64];
  __shared__ __align__(16) unsigned short Bs[128 * 64];
  __shared__ float pls[128][2], plss[128][2];
  const int tid = threadIdx.x;
  const int bm = blockIdx.x * 128;
  const int lane = tid & 63;
  const int wr = (tid >> 6) >> 1, wc = (tid >> 6) & 1;
  f32x4 acc[4][4] = {};
  const int nkt = K >> 6;
  for (int kt = 0; kt < nkt; ++kt) {
#pragma unroll
    for (int i = 0; i < 4; ++i) {
      int c = tid + i * 256;
      int row = c >> 3;
      int j = (c & 7) ^ (row & 7);
      int ar = bm + row; ar = ar < Nr ? ar : Nr - 1;
      gload_lds16(A + (size_t)ar * K + kt * 64 + j * 8, As + (size_t)c * 8);
      gload_lds16(Wt + (size_t)row * K + kt * 64 + j * 8, Bs + (size_t)c * 8);
    }
    __syncthreads();
#pragma unroll
    for (int ks = 0; ks < 2; ++ks) {
      bf16x8 af[4], bfr[4];
#pragma unroll
      for (int f = 0; f < 4; ++f) {
        int rowa = wr * 64 + f * 16 + (lane & 15);
        int ja = (ks * 4 + (lane >> 4)) ^ (rowa & 7);
        af[f] = *(const bf16x8*)(As + rowa * 64 + ja * 8);
        int rowb = wc * 64 + f * 16 + (lane & 15);
        int jb = (ks * 4 + (lane >> 4)) ^ (rowb & 7);
        bfr[f] = *(const bf16x8*)(Bs + rowb * 64 + jb * 8);
      }
#pragma unroll
      for (int fr = 0; fr < 4; ++fr)
#pragma unroll
        for (int fc = 0; fc < 4; ++fc)
          acc[fr][fc] = __builtin_amdgcn_mfma_f32_16x16x32_bf16(af[fr], bfr[fc], acc[fr][fc], 0, 0, 0);
    }
    __syncthreads();
  }
#pragma unroll
  for (int fr = 0; fr < 4; ++fr) {
#pragma unroll
    for (int j = 0; j < 4; ++j) {
      const int rl = wr * 64 + fr * 16 + (lane >> 4) * 4 + j;
      const int row = bm + rl;
      const int rowc = row < Nr ? row : Nr - 1;
      float s = 0.f, ss = 0.f;
#pragma unroll
      for (int fc = 0; fc < 4; ++fc) {
        int col = wc * 64 + fc * 16 + (lane & 15);
        float rv = RESBF ? bf2f(((const unsigned short*)res)[(size_t)rowc * 128 + col])
                         : ((const float*)res)[(size_t)rowc * 128 + col];
        float val = acc[fr][fc][j] + bias[col] + rv;
        acc[fr][fc][j] = val;
        s += val; ss += val * val;
      }
      s += __shfl_xor(s, 1); ss += __shfl_xor(ss, 1);
      s += __shfl_xor(s, 2); ss += __shfl_xor(ss, 2);
      s += __shfl_xor(s, 4); ss += __shfl_xor(ss, 4);
      s += __shfl_xor(s, 8); ss += __shfl_xor(ss, 8);
      if ((lane & 15) == 0) { pls[rl][wc] = s; plss[rl][wc] = ss; }
    }
  }
  __syncthreads();
#pragma unroll
  for (int fr = 0; fr < 4; ++fr) {
#pragma unroll
    for (int j = 0; j < 4; ++j) {
      const int rl = wr * 64 + fr * 16 + (lane >> 4) * 4 + j;
      const int row = bm + rl;
      if (row >= Nr) continue;
      const float S = pls[rl][0] + pls[rl][1];
      const float SS = plss[rl][0] + plss[rl][1];
      const float mu = S * (1.f / 128.f);
      const float inv = rsqrtf(SS * (1.f / 128.f) - mu * mu + LN_EPS);
#pragma unroll
      for (int fc = 0; fc < 4; ++fc) {
        int col = wc * 64 + fc * 16 + (lane & 15);
        float o = (acc[fr][fc][j] - mu) * inv * g[col] + b[col];
        if (WF32) y[(size_t)row * 128 + col] = o;
        if (WBF)  ybf[(size_t)row * 128 + col] = f2bf(o);
      }
    }
  }
}

// ---------------- edge pass 1: histogram + edge bias (coalesced) ----------------
__global__ __launch_bounds__(256)
void edge_hist_bias(const int* __restrict__ ei, const float* __restrict__ ea,
                    const float* __restrict__ eW, const float* __restrict__ eb,
                    int* __restrict__ deg, unsigned short* __restrict__ ebias_seq, int E) {
  __shared__ float ews[256];
  __shared__ float ebs[8];
  const int tid = threadIdx.x;
  if (tid < 256) ews[tid] = eW[tid];
  if (tid < 8) ebs[tid] = eb[tid];
  __syncthreads();
  int e = blockIdx.x * 256 + tid;
  if (e >= E) return;
  atomicAdd(&deg[ei[E + e]], 1);
  float bias[8];
#pragma unroll
  for (int h = 0; h < 8; ++h) bias[h] = ebs[h];
#pragma unroll
  for (int i4 = 0; i4 < 8; ++i4) {
    float4 a = *(const float4*)&ea[(size_t)e * 32 + i4 * 4];
    float av[4] = {a.x, a.y, a.z, a.w};
#pragma unroll
    for (int j = 0; j < 4; ++j)
#pragma unroll
      for (int h = 0; h < 8; ++h) bias[h] += av[j] * ews[(i4 * 4 + j) * 8 + h];
  }
  union { unsigned short us[8]; uint4 v; } pk;
#pragma unroll
  for (int h = 0; h < 8; ++h) pk.us[h] = f2bf(bias[h]);
  *(uint4*)&ebias_seq[(size_t)e * 8] = pk.v;
}

__global__ __launch_bounds__(256)
void deg_block_sum(const int* __restrict__ deg, int* __restrict__ bsum, int N) {
  const int t = threadIdx.x;
  const int beg = blockIdx.x * 2048 + t * 8;
  int s = 0;
#pragma unroll
  for (int j = 0; j < 8; ++j) { int i = beg + j; if (i < N) s += deg[i]; }
#pragma unroll
  for (int off = 32; off; off >>= 1) s += __shfl_xor(s, off);
  __shared__ int ws[4];
  if ((t & 63) == 0) ws[t >> 6] = s;
  __syncthreads();
  if (t == 0) bsum[blockIdx.x] = ws[0] + ws[1] + ws[2] + ws[3];
}

__global__ __launch_bounds__(64)
void scan_bsum(int* __restrict__ bsum, int* __restrict__ offs_last, int nb) {
  const int t = threadIdx.x;
  int v = (t < nb) ? bsum[t] : 0;
  int inc = v;
#pragma unroll
  for (int off = 1; off < 64; off <<= 1) {
    int x = __shfl_up(inc, off);
    if (t >= off) inc += x;
  }
  if (t < nb) bsum[t] = inc - v;
  if (t == 63) *offs_last = inc;
}

__global__ __launch_bounds__(256)
void deg_scan_write(const int* __restrict__ deg, const int* __restrict__ bsum,
                    int* __restrict__ offs, int* __restrict__ pos, int N) {
  const int t = threadIdx.x;
  const int beg = blockIdx.x * 2048 + t * 8;
  int loc[8]; int T = 0;
#pragma unroll
  for (int j = 0; j < 8; ++j) { int i = beg + j; loc[j] = (i < N) ? deg[i] : 0; T += loc[j]; }
  int inc = T;
#pragma unroll
  for (int off = 1; off < 64; off <<= 1) {
    int x = __shfl_up(inc, off);
    if ((t & 63) >= off) inc += x;
  }
  __shared__ int ws[4];
  if ((t & 63) == 63) ws[t >> 6] = inc;
  __syncthreads();
  const int wid = t >> 6;
  int wbase = 0;
  for (int w = 0; w < wid; ++w) wbase += ws[w];
  int base = bsum[blockIdx.x] + wbase + inc - T;
#pragma unroll
  for (int j = 0; j < 8; ++j) {
    int i = beg + j;
    if (i < N) { offs[i] = base; pos[i] = base; base += loc[j]; }
  }
}

// ------- edge pass 2: XCD-partitioned permute of (src, bias) into CSR order -------
// part = blockIdx & 7 maps round-robin to XCDs; each partition owns a contiguous dst
// range, so its csr/ebp output lines are dirtied by ONE XCD only (write-back once).
__global__ __launch_bounds__(256)
void edge_scatter_part(const int* __restrict__ ei, int* __restrict__ pos,
                       const unsigned short* __restrict__ ebias_seq,
                       int* __restrict__ csr_src, unsigned short* __restrict__ ebp,
                       int E, int N) {
  const int part = blockIdx.x & 7;
  const int slice = blockIdx.x >> 3;
  const int nslice = gridDim.x >> 3;
  const int per = (E + nslice - 1) / nslice;
  const int lo = slice * per;
  const int hi = min(E, lo + per);
  const int drange = (N + 7) >> 3;
  const int dlo = part * drange;
  const int dhi = min(N, dlo + drange);
  for (int e = lo + threadIdx.x; e < hi; e += 256) {
    int d = ei[E + e];
    if (d < dlo || d >= dhi) continue;
    int s = ei[e];
    uint4 bi = *(const uint4*)&ebias_seq[(size_t)e * 8];
    int p = atomicAdd(&pos[d], 1);
    csr_src[p] = s;
    *(uint4*)&ebp[(size_t)p * 8] = bi;
  }
}

// ---------------- fused per-node attention aggregate (sequential ebp) ----------------
__global__ __launch_bounds__(256)
void node_agg(const int* __restrict__ csr_src, const int* __restrict__ offs,
              const unsigned short* __restrict__ qkv, const unsigned short* __restrict__ ebp,
              unsigned short* __restrict__ agg, int N) {
  const int wid = threadIdx.x >> 6, lane = threadIdx.x & 63;
  const int h = lane >> 3;
  const long n = (long)blockIdx.x * 4 + wid;
  if (n >= N) return;
  const int off = offs[n], end = offs[n + 1];
  const ushort2 kv2 = *(const ushort2*)&qkv[(size_t)n * 384 + 128 + lane * 2];
  const float k0 = bf2f(kv2.x), k1 = bf2f(kv2.y);
  float acc0 = 0.f, acc1 = 0.f, den = 0.f;
  int i = off;
  for (; i + 8 <= end; i += 8) {
    size_t bb[8];
#pragma unroll
    for (int u = 0; u < 8; ++u) bb[u] = (size_t)csr_src[i + u] * 384;
    ushort2 qv[8], vv[8];
#pragma unroll
    for (int u = 0; u < 8; ++u) qv[u] = *(const ushort2*)&qkv[bb[u] + lane * 2];
#pragma unroll
    for (int u = 0; u < 8; ++u) vv[u] = *(const ushort2*)&qkv[bb[u] + 256 + lane * 2];
    float ebv[8];
#pragma unroll
    for (int u = 0; u < 8; ++u) ebv[u] = bf2f(ebp[(size_t)(i + u) * 8 + h]);
    float p[8];
#pragma unroll
    for (int u = 0; u < 8; ++u) p[u] = bf2f(qv[u].x) * k0 + bf2f(qv[u].y) * k1;
#pragma unroll
    for (int u = 0; u < 8; ++u) {
      p[u] += __shfl_xor(p[u], 1);
      p[u] += __shfl_xor(p[u], 2);
      p[u] += __shfl_xor(p[u], 4);
    }
#pragma unroll
    for (int u = 0; u < 8; ++u) {
      const float ex = __expf(p[u] * 0.25f + ebv[u]);
      den += ex;
      acc0 += bf2f(vv[u].x) * ex;
      acc1 += bf2f(vv[u].y) * ex;
    }
  }
  for (; i + 4 <= end; i += 4) {
    size_t bb[4];
#pragma unroll
    for (int u = 0; u < 4; ++u) bb[u] = (size_t)csr_src[i + u] * 384;
    ushort2 qv[4], vv[4];
#pragma unroll
    for (int u = 0; u < 4; ++u) qv[u] = *(const ushort2*)&qkv[bb[u] + lane * 2];
#pragma unroll
    for (int u = 0; u < 4; ++u) vv[u] = *(const ushort2*)&qkv[bb[u] + 256 + lane * 2];
    float ebv[4];
#pragma unroll
    for (int u = 0; u < 4; ++u) ebv[u] = bf2f(ebp[(size_t)(i + u) * 8 + h]);
    float p[4];
#pragma unroll
    for (int u = 0; u < 4; ++u) p[u] = bf2f(qv[u].x) * k0 + bf2f(qv[u].y) * k1;
#pragma unroll
    for (int u = 0; u < 4; ++u) {
      p[u] += __shfl_xor(p[u], 1);
      p[u] += __shfl_xor(p[u], 2);
      p[u] += __shfl_xor(p[u], 4);
    }
#pragma unroll
    for (int u = 0; u < 4; ++u) {
      const float ex = __expf(p[u] * 0.25f + ebv[u]);
      den += ex;
      acc0 += bf2f(vv[u].x) * ex;
      acc1 += bf2f(vv[u].y) * ex;
    }
  }
  for (; i < end; ++i) {
    const size_t b0 = (size_t)csr_src[i] * 384;
    const ushort2 qa = *(const ushort2*)&qkv[b0 + lane * 2];
    const ushort2 va = *(const ushort2*)&qkv[b0 + 256 + lane * 2];
    float p = bf2f(qa.x) * k0 + bf2f(qa.y) * k1;
    p += __shfl_xor(p, 1);
    p += __shfl_xor(p, 2);
    p += __shfl_xor(p, 4);
    const float ex = __expf(p * 0.25f + bf2f(ebp[(size_t)i * 8 + h]));
    den += ex;
    acc0 += bf2f(va.x) * ex;
    acc1 += bf2f(va.y) * ex;
  }
  const float r = 1.f / fmaxf(den, 1e-8f);
  ushort2 o; o.x = f2bf(acc0 * r); o.y = f2bf(acc1 * r);
  *(ushort2*)&agg[(size_t)n * 128 + lane * 2] = o;
}

// ---------------- in-place LN(row of 512) -> exact GELU, bf16 ----------------
__global__ __launch_bounds__(256)
void ln_gelu512(unsigned short* __restrict__ hbuf, const float* __restrict__ g,
                const float* __restrict__ b, int Nr) {
  __shared__ float rs[4], rss[4];
  const long row = blockIdx.x;
  const int tid = threadIdx.x;
  ushort2 u = *(ushort2*)&hbuf[row * 512 + tid * 2];
  float v0 = bf2f(u.x), v1 = bf2f(u.y);
  float s = v0 + v1, ss = v0 * v0 + v1 * v1;
#pragma unroll
  for (int off = 32; off; off >>= 1) { s += __shfl_xor(s, off); ss += __shfl_xor(ss, off); }
  const int wid = tid >> 6, lane = tid & 63;
  if (lane == 0) { rs[wid] = s; rss[wid] = ss; }
  __syncthreads();
  s = rs[0] + rs[1] + rs[2] + rs[3];
  ss = rss[0] + rss[1] + rss[2] + rss[3];
  const float mu = s * (1.f / 512.f);
  const float inv = rsqrtf(ss * (1.f / 512.f) - mu * mu + LN_EPS);
  float t0 = (v0 - mu) * inv * g[tid * 2] + b[tid * 2];
  float t1 = (v1 - mu) * inv * g[tid * 2 + 1] + b[tid * 2 + 1];
  t0 = 0.5f * t0 * (1.f + erff(t0 * 0.70710678118654752f));
  t1 = 0.5f * t1 * (1.f + erff(t1 * 0.70710678118654752f));
  ushort2 o; o.x = f2bf(t0); o.y = f2bf(t1);
  *(ushort2*)&hbuf[row * 512 + tid * 2] = o;
}

extern "C" void kernel_launch(void* const* d_in, const int* in_sizes, int n_in,
                              void* d_out, int out_size, void* d_ws, size_t ws_size,
                              hipStream_t stream) {
  const float* x   = (const float*)d_in[0];
  const int*   ei  = (const int*)d_in[1];
  const float* ea  = (const float*)d_in[2];
  const float* qW  = (const float*)d_in[3];
  const float* qbi = (const float*)d_in[4];
  const float* kW  = (const float*)d_in[5];
  const float* kbi = (const float*)d_in[6];
  const float* vW  = (const float*)d_in[7];
  const float* vbi = (const float*)d_in[8];
  const float* eW  = (const float*)d_in[9];
  const float* eb  = (const float*)d_in[10];
  const float* oW  = (const float*)d_in[11];
  const float* ob  = (const float*)d_in[12];
  const float* ln1_g = (const float*)d_in[13];
  const float* ln1_b = (const float*)d_in[14];
  const float* f1W = (const float*)d_in[15];
  const float* f1b = (const float*)d_in[16];
  const float* lnf_g = (const float*)d_in[17];
  const float* lnf_b = (const float*)d_in[18];
  const float* f2W = (const float*)d_in[19];
  const float* f2b = (const float*)d_in[20];
  const float* ln2_g = (const float*)d_in[21];
  const float* ln2_b = (const float*)d_in[22];
  float* out = (float*)d_out;

  const int N = in_sizes[0] / 128;
  const int E = in_sizes[1] / 2;
  const size_t NH = (size_t)N * 128;   // 6.4M floats

  // workspace (float units), lifetime-overlapped:
  //  [0, .5NH)      xbf bf16 -> x1bf
  //  [.5NH, 2NH)    qkv bf16 [N][384]; hbuf bf16 [N][512] overlays [.5NH, 2.5NH) (FFN)
  //  [2NH, 2.5NH)   ebp bf16 [E][8] (dead before f1)
  //  [2.5NH, 3NH)   aggb bf16
  //  [3NH, 3.5NH)   ebias_seq bf16 [E][8]
  //  [4NH, ...)     ints: csr_src E, offs N+1, pos N, bsum; then bf16 weights + bias
  float* F = (float*)d_ws;
  unsigned short* xbf   = (unsigned short*)F;
  unsigned short* qkvb  = (unsigned short*)(F + NH / 2);
  unsigned short* ebp   = (unsigned short*)(F + 2 * NH);
  unsigned short* aggb  = (unsigned short*)(F + 2 * NH + NH / 2);
  unsigned short* ebias_seq = (unsigned short*)(F + 3 * NH);
  unsigned short* x1bf  = xbf;
  unsigned short* hbufb = (unsigned short*)(F + NH / 2);
  int* ib      = (int*)(F + 4 * NH);
  int* csr_src = ib;
  int* offs    = ib + E;
  int* pos     = ib + E + N + 1;
  int* bsum    = ib + E + 2 * N + 1;
  unsigned short* wt = (unsigned short*)(ib + E + 2 * N + 128);
  unsigned short* qkvWt = wt;            // 384x128
  unsigned short* oWt   = wt + 49152;    // 128x128
  unsigned short* f1Wt  = wt + 65536;    // 512x128
  unsigned short* f2Wt  = wt + 131072;   // 128x512
  float* qkvbias = (float*)(wt + 196608);

  dim3 blk(256);
  dim3 gqkv((N + 127) / 128, 3);
  dim3 g128((N + 127) / 128, 1);
  dim3 gf1((N + 127) / 128, 4);
  const int nb = (N + 2047) / 2048;
  const int ge = (E + 255) / 256;
  const int gA = (int)((NH / 4 + 255) / 256);
  const int gZ = (N + 1023) / 1024;

  // front: to_bf16 + pos-zero + all weight prep in ONE launch
  front<<<dim3(gA + gZ + 193), blk, 0, stream>>>(x, xbf, (long)NH, pos, N, gA, gZ,
                                                 qW, kW, vW, oW, f1W, f2W,
                                                 qkvWt, oWt, f1Wt, f2Wt,
                                                 qbi, kbi, vbi, qkvbias);

  // merged QKV projection -> qkv[N][384] bf16
  gemm_mfma<true><<<gqkv, blk, 0, stream>>>(xbf, qkvWt, qkvbias, qkvb, N, 128, 384);

  // edge pass 1 (hist + bias) -> scans -> pass 2 (XCD-partitioned permute)
  edge_hist_bias<<<dim3(ge), blk, 0, stream>>>(ei, ea, eW, eb, pos, ebias_seq, E);
  deg_block_sum<<<dim3(nb), blk, 0, stream>>>(pos, bsum, N);
  scan_bsum<<<dim3(1), dim3(64), 0, stream>>>(bsum, offs + N, nb);
  deg_scan_write<<<dim3(nb), blk, 0, stream>>>(pos, bsum, offs, pos, N);
  edge_scatter_part<<<dim3(1024), blk, 0, stream>>>(ei, pos, ebias_seq, csr_src, ebp, E, N);

  // fused attention aggregate (one wave per node, static)
  node_agg<<<dim3((N + 3) / 4), blk, 0, stream>>>(csr_src, offs, qkvb, ebp, aggb, N);

  // output projection fused with residual LN1 -> x1bf (bf16 residual from xbf)
  gemm_ln<false, true, true><<<g128, blk, 0, stream>>>(aggb, oWt, ob, xbf,
                                                       ln1_g, ln1_b, nullptr, x1bf, N, 128);

  // FFN: f1 GEMM, LN+GELU, f2 + LN2 -> out
  gemm_mfma<true><<<gf1, blk, 0, stream>>>(x1bf, f1Wt, f1b, hbufb, N, 128, 512);
  ln_gelu512<<<dim3(N), blk, 0, stream>>>(hbufb, lnf_g, lnf_b, N);
  gemm_ln<true, false, true><<<g128, blk, 0, stream>>>(hbufb, f2Wt, f2b, x1bf,
                                                       ln2_g, ln2_b, out, nullptr, N, 512);
}

// Round 15
// 293.846 us; speedup vs baseline: 1.7252x; 1.0204x over previous
//
#include <hip/hip_runtime.h>
#include <math.h>

#define LN_EPS 1e-5f

typedef __attribute__((ext_vector_type(8))) __bf16 bf16x8;
typedef __attribute__((ext_vector_type(4))) float f32x4;

__device__ inline float bf2f(unsigned short u) {
  union { unsigned int i; float f; } x; x.i = ((unsigned int)u) << 16; return x.f;
}
__device__ inline unsigned short f2bf(float f) {
  union { float f; unsigned int i; } x; x.f = f;
  unsigned int r = (x.i + 0x7FFFu + ((x.i >> 16) & 1u)) >> 16;   // RNE
  return (unsigned short)r;
}
__device__ inline void gload_lds16(const void* g, void* l) {
  __builtin_amdgcn_global_load_lds((const __attribute__((address_space(1))) void*)g,
                                   (__attribute__((address_space(3))) void*)l, 16, 0, 0);
}

// ------- front: to_bf16 ∪ pos-zero ∪ all weight transposes + bias concat, one launch -------
__global__ __launch_bounds__(256)
void front(const float* __restrict__ x, unsigned short* __restrict__ xbf, long n,
           int* __restrict__ pos, int N, int gA, int gZ,
           const float* qW, const float* kW, const float* vW, const float* oW,
           const float* f1W, const float* f2W,
           unsigned short* qkvWt, unsigned short* oWt,
           unsigned short* f1Wt, unsigned short* f2Wt,
           const float* qb, const float* kb, const float* vb, float* qkvbias) {
  const int b = blockIdx.x;
  const int tid = threadIdx.x;
  if (b < gA) {                       // f32 -> bf16
    long i = ((long)b * 256 + tid) * 4;
    if (i >= n) return;
    float4 v = *(const float4*)&x[i];
    ushort4 o = { f2bf(v.x), f2bf(v.y), f2bf(v.z), f2bf(v.w) };
    *(ushort4*)&xbf[i] = o;
    return;
  }
  if (b < gA + gZ) {                  // zero pos[N]
    int base = (b - gA) * 1024 + tid * 4;
    if (base + 3 < N) *(int4*)(pos + base) = make_int4(0, 0, 0, 0);
    else for (int j = 0; j < 4; ++j) if (base + j < N) pos[base + j] = 0;
    return;
  }
  const int t = b - gA - gZ;          // weight prep tiles
  if (t == 192) {
    int i = tid;
    if (i < 128) { qkvbias[i] = qb[i]; qkvbias[128 + i] = kb[i]; }
    else if (i < 256) qkvbias[256 + (i - 128)] = vb[i - 128];
    return;
  }
  const float* W; unsigned short* Wt; int K, M, lt;
  if (t < 64)       { K = 128; M = 128; lt = t & 15;
    if (t < 16)      { W = qW; Wt = qkvWt; }
    else if (t < 32) { W = kW; Wt = qkvWt + 16384; }
    else if (t < 48) { W = vW; Wt = qkvWt + 32768; }
    else             { W = oW; Wt = oWt; } }
  else if (t < 128) { K = 128; M = 512; lt = t - 64; W = f1W; Wt = f1Wt; }
  else              { K = 512; M = 128; lt = t - 128; W = f2W; Wt = f2Wt; }
  const int ktiles = K >> 5;
  const int k0 = (lt % ktiles) * 32, m0 = (lt / ktiles) * 32;
  __shared__ float tb[32][33];
  const int tx = tid & 31, ty = tid >> 5;  // 32 x 8
#pragma unroll
  for (int i = 0; i < 32; i += 8)
    tb[ty + i][tx] = W[(size_t)(k0 + ty + i) * M + m0 + tx];
  __syncthreads();
#pragma unroll
  for (int i = 0; i < 32; i += 8)
    Wt[(size_t)(m0 + ty + i) * K + k0 + tx] = f2bf(tb[tx][ty + i]);
}

// ---------------- bf16 MFMA GEMM: C[N,M] = A[N,K] @ Wt[M,K]^T + bias ----------------
template<bool OBF>
__global__ __launch_bounds__(256)
void gemm_mfma(const unsigned short* __restrict__ A, const unsigned short* __restrict__ Wt,
               const float* __restrict__ bias, void* __restrict__ Cout,
               int Nr, int K, int M) {
  __shared__ __align__(16) unsigned short As[128 * 64];
  __shared__ __align__(16) unsigned short Bs[128 * 64];
  const int tid = threadIdx.x;
  const int bm = blockIdx.x * 128, bn = blockIdx.y * 128;
  const int lane = tid & 63;
  const int wr = (tid >> 6) >> 1, wc = (tid >> 6) & 1;
  f32x4 acc[4][4] = {};
  const int nkt = K >> 6;
  for (int kt = 0; kt < nkt; ++kt) {
#pragma unroll
    for (int i = 0; i < 4; ++i) {
      int c = tid + i * 256;
      int row = c >> 3;
      int j = (c & 7) ^ (row & 7);
      int ar = bm + row; ar = ar < Nr ? ar : Nr - 1;
      gload_lds16(A + (size_t)ar * K + kt * 64 + j * 8, As + (size_t)c * 8);
      gload_lds16(Wt + (size_t)(bn + row) * K + kt * 64 + j * 8, Bs + (size_t)c * 8);
    }
    __syncthreads();
#pragma unroll
    for (int ks = 0; ks < 2; ++ks) {
      bf16x8 af[4], bfr[4];
#pragma unroll
      for (int f = 0; f < 4; ++f) {
        int rowa = wr * 64 + f * 16 + (lane & 15);
        int ja = (ks * 4 + (lane >> 4)) ^ (rowa & 7);
        af[f] = *(const bf16x8*)(As + rowa * 64 + ja * 8);
        int rowb = wc * 64 + f * 16 + (lane & 15);
        int jb = (ks * 4 + (lane >> 4)) ^ (rowb & 7);
        bfr[f] = *(const bf16x8*)(Bs + rowb * 64 + jb * 8);
      }
#pragma unroll
      for (int fr = 0; fr < 4; ++fr)
#pragma unroll
        for (int fc = 0; fc < 4; ++fc)
          acc[fr][fc] = __builtin_amdgcn_mfma_f32_16x16x32_bf16(af[fr], bfr[fc], acc[fr][fc], 0, 0, 0);
    }
    __syncthreads();
  }
#pragma unroll
  for (int fr = 0; fr < 4; ++fr) {
#pragma unroll
    for (int j = 0; j < 4; ++j) {
      int row = bm + wr * 64 + fr * 16 + (lane >> 4) * 4 + j;
      if (row < Nr) {
#pragma unroll
        for (int fc = 0; fc < 4; ++fc) {
          int col = bn + wc * 64 + fc * 16 + (lane & 15);
          float v = acc[fr][fc][j] + bias[col];
          if (OBF) ((unsigned short*)Cout)[(size_t)row * M + col] = f2bf(v);
          else     ((float*)Cout)[(size_t)row * M + col] = v;
        }
      }
    }
  }
}

// ------- bf16 MFMA GEMM (M=128) fused with y = LN(res + A@Wt^T + bias) -------
template<bool WF32, bool WBF, bool RESBF>
__global__ __launch_bounds__(256)
void gemm_ln(const unsigned short* __restrict__ A, const unsigned short* __restrict__ Wt,
             const float* __restrict__ bias, const void* __restrict__ res,
             const float* __restrict__ g, const float* __restrict__ b,
             float* __restrict__ y, unsigned short* __restrict__ ybf, int Nr, int K) {
  __shared__ __align__(16) unsigned short As[128 * 64];
  __shared__ __align__(16) unsigned short Bs[128 * 64];
  __shared__ float pls[128][2], plss[128][2];
  const int tid = threadIdx.x;
  const int bm = blockIdx.x * 128;
  const int lane = tid & 63;
  const int wr = (tid >> 6) >> 1, wc = (tid >> 6) & 1;
  f32x4 acc[4][4] = {};
  const int nkt = K >> 6;
  for (int kt = 0; kt < nkt; ++kt) {
#pragma unroll
    for (int i = 0; i < 4; ++i) {
      int c = tid + i * 256;
      int row = c >> 3;
      int j = (c & 7) ^ (row & 7);
      int ar = bm + row; ar = ar < Nr ? ar : Nr - 1;
      gload_lds16(A + (size_t)ar * K + kt * 64 + j * 8, As + (size_t)c * 8);
      gload_lds16(Wt + (size_t)row * K + kt * 64 + j * 8, Bs + (size_t)c * 8);
    }
    __syncthreads();
#pragma unroll
    for (int ks = 0; ks < 2; ++ks) {
      bf16x8 af[4], bfr[4];
#pragma unroll
      for (int f = 0; f < 4; ++f) {
        int rowa = wr * 64 + f * 16 + (lane & 15);
        int ja = (ks * 4 + (lane >> 4)) ^ (rowa & 7);
        af[f] = *(const bf16x8*)(As + rowa * 64 + ja * 8);
        int rowb = wc * 64 + f * 16 + (lane & 15);
        int jb = (ks * 4 + (lane >> 4)) ^ (rowb & 7);
        bfr[f] = *(const bf16x8*)(Bs + rowb * 64 + jb * 8);
      }
#pragma unroll
      for (int fr = 0; fr < 4; ++fr)
#pragma unroll
        for (int fc = 0; fc < 4; ++fc)
          acc[fr][fc] = __builtin_amdgcn_mfma_f32_16x16x32_bf16(af[fr], bfr[fc], acc[fr][fc], 0, 0, 0);
    }
    __syncthreads();
  }
#pragma unroll
  for (int fr = 0; fr < 4; ++fr) {
#pragma unroll
    for (int j = 0; j < 4; ++j) {
      const int rl = wr * 64 + fr * 16 + (lane >> 4) * 4 + j;
      const int row = bm + rl;
      const int rowc = row < Nr ? row : Nr - 1;
      float s = 0.f, ss = 0.f;
#pragma unroll
      for (int fc = 0; fc < 4; ++fc) {
        int col = wc * 64 + fc * 16 + (lane & 15);
        float rv = RESBF ? bf2f(((const unsigned short*)res)[(size_t)rowc * 128 + col])
                         : ((const float*)res)[(size_t)rowc * 128 + col];
        float val = acc[fr][fc][j] + bias[col] + rv;
        acc[fr][fc][j] = val;
        s += val; ss += val * val;
      }
      s += __shfl_xor(s, 1); ss += __shfl_xor(ss, 1);
      s += __shfl_xor(s, 2); ss += __shfl_xor(ss, 2);
      s += __shfl_xor(s, 4); ss += __shfl_xor(ss, 4);
      s += __shfl_xor(s, 8); ss += __shfl_xor(ss, 8);
      if ((lane & 15) == 0) { pls[rl][wc] = s; plss[rl][wc] = ss; }
    }
  }
  __syncthreads();
#pragma unroll
  for (int fr = 0; fr < 4; ++fr) {
#pragma unroll
    for (int j = 0; j < 4; ++j) {
      const int rl = wr * 64 + fr * 16 + (lane >> 4) * 4 + j;
      const int row = bm + rl;
      if (row >= Nr) continue;
      const float S = pls[rl][0] + pls[rl][1];
      const float SS = plss[rl][0] + plss[rl][1];
      const float mu = S * (1.f / 128.f);
      const float inv = rsqrtf(SS * (1.f / 128.f) - mu * mu + LN_EPS);
#pragma unroll
      for (int fc = 0; fc < 4; ++fc) {
        int col = wc * 64 + fc * 16 + (lane & 15);
        float o = (acc[fr][fc][j] - mu) * inv * g[col] + b[col];
        if (WF32) y[(size_t)row * 128 + col] = o;
        if (WBF)  ybf[(size_t)row * 128 + col] = f2bf(o);
      }
    }
  }
}

// ---------------- edge pass 1: histogram + edge bias (coalesced) ----------------
__global__ __launch_bounds__(256)
void edge_hist_bias(const int* __restrict__ ei, const float* __restrict__ ea,
                    const float* __restrict__ eW, const float* __restrict__ eb,
                    int* __restrict__ deg, unsigned short* __restrict__ ebias_seq, int E) {
  __shared__ float ews[256];
  __shared__ float ebs[8];
  const int tid = threadIdx.x;
  if (tid < 256) ews[tid] = eW[tid];
  if (tid < 8) ebs[tid] = eb[tid];
  __syncthreads();
  int e = blockIdx.x * 256 + tid;
  if (e >= E) return;
  atomicAdd(&deg[ei[E + e]], 1);
  float bias[8];
#pragma unroll
  for (int h = 0; h < 8; ++h) bias[h] = ebs[h];
#pragma unroll
  for (int i4 = 0; i4 < 8; ++i4) {
    float4 a = *(const float4*)&ea[(size_t)e * 32 + i4 * 4];
    float av[4] = {a.x, a.y, a.z, a.w};
#pragma unroll
    for (int j = 0; j < 4; ++j)
#pragma unroll
      for (int h = 0; h < 8; ++h) bias[h] += av[j] * ews[(i4 * 4 + j) * 8 + h];
  }
  union { unsigned short us[8]; uint4 v; } pk;
#pragma unroll
  for (int h = 0; h < 8; ++h) pk.us[h] = f2bf(bias[h]);
  *(uint4*)&ebias_seq[(size_t)e * 8] = pk.v;
}

__global__ __launch_bounds__(256)
void deg_block_sum(const int* __restrict__ deg, int* __restrict__ bsum, int N) {
  const int t = threadIdx.x;
  const int beg = blockIdx.x * 2048 + t * 8;
  int s = 0;
#pragma unroll
  for (int j = 0; j < 8; ++j) { int i = beg + j; if (i < N) s += deg[i]; }
#pragma unroll
  for (int off = 32; off; off >>= 1) s += __shfl_xor(s, off);
  __shared__ int ws[4];
  if ((t & 63) == 0) ws[t >> 6] = s;
  __syncthreads();
  if (t == 0) bsum[blockIdx.x] = ws[0] + ws[1] + ws[2] + ws[3];
}

__global__ __launch_bounds__(64)
void scan_bsum(int* __restrict__ bsum, int* __restrict__ offs_last, int nb) {
  const int t = threadIdx.x;
  int v = (t < nb) ? bsum[t] : 0;
  int inc = v;
#pragma unroll
  for (int off = 1; off < 64; off <<= 1) {
    int x = __shfl_up(inc, off);
    if (t >= off) inc += x;
  }
  if (t < nb) bsum[t] = inc - v;
  if (t == 63) *offs_last = inc;
}

__global__ __launch_bounds__(256)
void deg_scan_write(const int* __restrict__ deg, const int* __restrict__ bsum,
                    int* __restrict__ offs, int* __restrict__ pos, int N) {
  const int t = threadIdx.x;
  const int beg = blockIdx.x * 2048 + t * 8;
  int loc[8]; int T = 0;
#pragma unroll
  for (int j = 0; j < 8; ++j) { int i = beg + j; loc[j] = (i < N) ? deg[i] : 0; T += loc[j]; }
  int inc = T;
#pragma unroll
  for (int off = 1; off < 64; off <<= 1) {
    int x = __shfl_up(inc, off);
    if ((t & 63) >= off) inc += x;
  }
  __shared__ int ws[4];
  if ((t & 63) == 63) ws[t >> 6] = inc;
  __syncthreads();
  const int wid = t >> 6;
  int wbase = 0;
  for (int w = 0; w < wid; ++w) wbase += ws[w];
  int base = bsum[blockIdx.x] + wbase + inc - T;
#pragma unroll
  for (int j = 0; j < 8; ++j) {
    int i = beg + j;
    if (i < N) { offs[i] = base; pos[i] = base; base += loc[j]; }
  }
}

// ------- edge pass 2: XCD-partitioned permute of (src, bias) into CSR order -------
__global__ __launch_bounds__(256)
void edge_scatter_part(const int* __restrict__ ei, int* __restrict__ pos,
                       const unsigned short* __restrict__ ebias_seq,
                       int* __restrict__ csr_src, unsigned short* __restrict__ ebp,
                       int E, int N) {
  const int part = blockIdx.x & 7;
  const int slice = blockIdx.x >> 3;
  const int nslice = gridDim.x >> 3;
  const int per = (E + nslice - 1) / nslice;
  const int lo = slice * per;
  const int hi = min(E, lo + per);
  const int drange = (N + 7) >> 3;
  const int dlo = part * drange;
  const int dhi = min(N, dlo + drange);
  for (int e = lo + threadIdx.x; e < hi; e += 256) {
    int d = ei[E + e];
    if (d < dlo || d >= dhi) continue;
    int s = ei[e];
    uint4 bi = *(const uint4*)&ebias_seq[(size_t)e * 8];
    int p = atomicAdd(&pos[d], 1);
    csr_src[p] = s;
    *(uint4*)&ebp[(size_t)p * 8] = bi;
  }
}

// ---------------- fused per-node attention aggregate (16-deep gather pipeline) ----------------
__global__ __launch_bounds__(256)
void node_agg(const int* __restrict__ csr_src, const int* __restrict__ offs,
              const unsigned short* __restrict__ qkv, const unsigned short* __restrict__ ebp,
              unsigned short* __restrict__ agg, int N) {
  const int wid = threadIdx.x >> 6, lane = threadIdx.x & 63;
  const int h = lane >> 3;
  const long n = (long)blockIdx.x * 4 + wid;
  if (n >= N) return;
  const int off = offs[n], end = offs[n + 1];
  const ushort2 kv2 = *(const ushort2*)&qkv[(size_t)n * 384 + 128 + lane * 2];
  const float k0 = bf2f(kv2.x), k1 = bf2f(kv2.y);
  float acc0 = 0.f, acc1 = 0.f, den = 0.f;
  int i = off;
  for (; i + 16 <= end; i += 16) {     // 16-wide: 32 independent q/v gathers in flight
    size_t bb[16];
#pragma unroll
    for (int u = 0; u < 16; ++u) bb[u] = (size_t)csr_src[i + u] * 384;
    ushort2 qv[16], vv[16];
#pragma unroll
    for (int u = 0; u < 16; ++u) qv[u] = *(const ushort2*)&qkv[bb[u] + lane * 2];
#pragma unroll
    for (int u = 0; u < 16; ++u) vv[u] = *(const ushort2*)&qkv[bb[u] + 256 + lane * 2];
    float ebv[16];
#pragma unroll
    for (int u = 0; u < 16; ++u) ebv[u] = bf2f(ebp[(size_t)(i + u) * 8 + h]);
    float p[16];
#pragma unroll
    for (int u = 0; u < 16; ++u) p[u] = bf2f(qv[u].x) * k0 + bf2f(qv[u].y) * k1;
#pragma unroll
    for (int u = 0; u < 16; ++u) {
      p[u] += __shfl_xor(p[u], 1);
      p[u] += __shfl_xor(p[u], 2);
      p[u] += __shfl_xor(p[u], 4);
    }
#pragma unroll
    for (int u = 0; u < 16; ++u) {
      const float ex = __expf(p[u] * 0.25f + ebv[u]);
      den += ex;
      acc0 += bf2f(vv[u].x) * ex;
      acc1 += bf2f(vv[u].y) * ex;
    }
  }
  for (; i + 8 <= end; i += 8) {
    size_t bb[8];
#pragma unroll
    for (int u = 0; u < 8; ++u) bb[u] = (size_t)csr_src[i + u] * 384;
    ushort2 qv[8], vv[8];
#pragma unroll
    for (int u = 0; u < 8; ++u) qv[u] = *(const ushort2*)&qkv[bb[u] + lane * 2];
#pragma unroll
    for (int u = 0; u < 8; ++u) vv[u] = *(const ushort2*)&qkv[bb[u] + 256 + lane * 2];
    float ebv[8];
#pragma unroll
    for (int u = 0; u < 8; ++u) ebv[u] = bf2f(ebp[(size_t)(i + u) * 8 + h]);
    float p[8];
#pragma unroll
    for (int u = 0; u < 8; ++u) p[u] = bf2f(qv[u].x) * k0 + bf2f(qv[u].y) * k1;
#pragma unroll
    for (int u = 0; u < 8; ++u) {
      p[u] += __shfl_xor(p[u], 1);
      p[u] += __shfl_xor(p[u], 2);
      p[u] += __shfl_xor(p[u], 4);
    }
#pragma unroll
    for (int u = 0; u < 8; ++u) {
      const float ex = __expf(p[u] * 0.25f + ebv[u]);
      den += ex;
      acc0 += bf2f(vv[u].x) * ex;
      acc1 += bf2f(vv[u].y) * ex;
    }
  }
  for (; i + 4 <= end; i += 4) {
    size_t bb[4];
#pragma unroll
    for (int u = 0; u < 4; ++u) bb[u] = (size_t)csr_src[i + u] * 384;
    ushort2 qv[4], vv[4];
#pragma unroll
    for (int u = 0; u < 4; ++u) qv[u] = *(const ushort2*)&qkv[bb[u] + lane * 2];
#pragma unroll
    for (int u = 0; u < 4; ++u) vv[u] = *(const ushort2*)&qkv[bb[u] + 256 + lane * 2];
    float ebv[4];
#pragma unroll
    for (int u = 0; u < 4; ++u) ebv[u] = bf2f(ebp[(size_t)(i + u) * 8 + h]);
    float p[4];
#pragma unroll
    for (int u = 0; u < 4; ++u) p[u] = bf2f(qv[u].x) * k0 + bf2f(qv[u].y) * k1;
#pragma unroll
    for (int u = 0; u < 4; ++u) {
      p[u] += __shfl_xor(p[u], 1);
      p[u] += __shfl_xor(p[u], 2);
      p[u] += __shfl_xor(p[u], 4);
    }
#pragma unroll
    for (int u = 0; u < 4; ++u) {
      const float ex = __expf(p[u] * 0.25f + ebv[u]);
      den += ex;
      acc0 += bf2f(vv[u].x) * ex;
      acc1 += bf2f(vv[u].y) * ex;
    }
  }
  for (; i < end; ++i) {
    const size_t b0 = (size_t)csr_src[i] * 384;
    const ushort2 qa = *(const ushort2*)&qkv[b0 + lane * 2];
    const ushort2 va = *(const ushort2*)&qkv[b0 + 256 + lane * 2];
    float p = bf2f(qa.x) * k0 + bf2f(qa.y) * k1;
    p += __shfl_xor(p, 1);
    p += __shfl_xor(p, 2);
    p += __shfl_xor(p, 4);
    const float ex = __expf(p * 0.25f + bf2f(ebp[(size_t)i * 8 + h]));
    den += ex;
    acc0 += bf2f(va.x) * ex;
    acc1 += bf2f(va.y) * ex;
  }
  const float r = 1.f / fmaxf(den, 1e-8f);
  ushort2 o; o.x = f2bf(acc0 * r); o.y = f2bf(acc1 * r);
  *(ushort2*)&agg[(size_t)n * 128 + lane * 2] = o;
}

// ---------------- wave-per-row LN(512) -> exact GELU, bf16, uint4 loads ----------------
__global__ __launch_bounds__(256)
void ln_gelu512(unsigned short* __restrict__ hbuf, const float* __restrict__ g,
                const float* __restrict__ b, int Nr) {
  const int wid = threadIdx.x >> 6, lane = threadIdx.x & 63;
  const long row = (long)blockIdx.x * 4 + wid;
  if (row >= Nr) return;
  union { uint4 v; unsigned short us[8]; } u;
  u.v = *(const uint4*)&hbuf[row * 512 + lane * 8];
  float f[8];
  float s = 0.f, ss = 0.f;
#pragma unroll
  for (int j = 0; j < 8; ++j) { f[j] = bf2f(u.us[j]); s += f[j]; ss += f[j] * f[j]; }
#pragma unroll
  for (int off = 32; off; off >>= 1) { s += __shfl_xor(s, off); ss += __shfl_xor(ss, off); }
  const float mu = s * (1.f / 512.f);
  const float inv = rsqrtf(ss * (1.f / 512.f) - mu * mu + LN_EPS);
  float4 g0 = *(const float4*)&g[lane * 8];
  float4 g1 = *(const float4*)&g[lane * 8 + 4];
  float4 b0 = *(const float4*)&b[lane * 8];
  float4 b1 = *(const float4*)&b[lane * 8 + 4];
  float gv[8] = {g0.x, g0.y, g0.z, g0.w, g1.x, g1.y, g1.z, g1.w};
  float bv[8] = {b0.x, b0.y, b0.z, b0.w, b1.x, b1.y, b1.z, b1.w};
#pragma unroll
  for (int j = 0; j < 8; ++j) {
    float t = (f[j] - mu) * inv * gv[j] + bv[j];
    t = 0.5f * t * (1.f + erff(t * 0.70710678118654752f));
    u.us[j] = f2bf(t);
  }
  *(uint4*)&hbuf[row * 512 + lane * 8] = u.v;
}

extern "C" void kernel_launch(void* const* d_in, const int* in_sizes, int n_in,
                              void* d_out, int out_size, void* d_ws, size_t ws_size,
                              hipStream_t stream) {
  const float* x   = (const float*)d_in[0];
  const int*   ei  = (const int*)d_in[1];
  const float* ea  = (const float*)d_in[2];
  const float* qW  = (const float*)d_in[3];
  const float* qbi = (const float*)d_in[4];
  const float* kW  = (const float*)d_in[5];
  const float* kbi = (const float*)d_in[6];
  const float* vW  = (const float*)d_in[7];
  const float* vbi = (const float*)d_in[8];
  const float* eW  = (const float*)d_in[9];
  const float* eb  = (const float*)d_in[10];
  const float* oW  = (const float*)d_in[11];
  const float* ob  = (const float*)d_in[12];
  const float* ln1_g = (const float*)d_in[13];
  const float* ln1_b = (const float*)d_in[14];
  const float* f1W = (const float*)d_in[15];
  const float* f1b = (const float*)d_in[16];
  const float* lnf_g = (const float*)d_in[17];
  const float* lnf_b = (const float*)d_in[18];
  const float* f2W = (const float*)d_in[19];
  const float* f2b = (const float*)d_in[20];
  const float* ln2_g = (const float*)d_in[21];
  const float* ln2_b = (const float*)d_in[22];
  float* out = (float*)d_out;

  const int N = in_sizes[0] / 128;
  const int E = in_sizes[1] / 2;
  const size_t NH = (size_t)N * 128;   // 6.4M floats

  // workspace (float units), lifetime-overlapped:
  //  [0, .5NH)      xbf bf16 -> x1bf
  //  [.5NH, 2NH)    qkv bf16 [N][384]; hbuf bf16 [N][512] overlays [.5NH, 2.5NH) (FFN)
  //  [2NH, 2.5NH)   ebp bf16 [E][8] (dead before f1)
  //  [2.5NH, 3NH)   aggb bf16
  //  [3NH, 3.5NH)   ebias_seq bf16 [E][8]
  //  [4NH, ...)     ints: csr_src E, offs N+1, pos N, bsum; then bf16 weights + bias
  float* F = (float*)d_ws;
  unsigned short* xbf   = (unsigned short*)F;
  unsigned short* qkvb  = (unsigned short*)(F + NH / 2);
  unsigned short* ebp   = (unsigned short*)(F + 2 * NH);
  unsigned short* aggb  = (unsigned short*)(F + 2 * NH + NH / 2);
  unsigned short* ebias_seq = (unsigned short*)(F + 3 * NH);
  unsigned short* x1bf  = xbf;
  unsigned short* hbufb = (unsigned short*)(F + NH / 2);
  int* ib      = (int*)(F + 4 * NH);
  int* csr_src = ib;
  int* offs    = ib + E;
  int* pos     = ib + E + N + 1;
  int* bsum    = ib + E + 2 * N + 1;
  unsigned short* wt = (unsigned short*)(ib + E + 2 * N + 128);
  unsigned short* qkvWt = wt;            // 384x128
  unsigned short* oWt   = wt + 49152;    // 128x128
  unsigned short* f1Wt  = wt + 65536;    // 512x128
  unsigned short* f2Wt  = wt + 131072;   // 128x512
  float* qkvbias = (float*)(wt + 196608);

  dim3 blk(256);
  dim3 gqkv((N + 127) / 128, 3);
  dim3 g128((N + 127) / 128, 1);
  dim3 gf1((N + 127) / 128, 4);
  const int nb = (N + 2047) / 2048;
  const int ge = (E + 255) / 256;
  const int gA = (int)((NH / 4 + 255) / 256);
  const int gZ = (N + 1023) / 1024;

  // front: to_bf16 + pos-zero + all weight prep in ONE launch
  front<<<dim3(gA + gZ + 193), blk, 0, stream>>>(x, xbf, (long)NH, pos, N, gA, gZ,
                                                 qW, kW, vW, oW, f1W, f2W,
                                                 qkvWt, oWt, f1Wt, f2Wt,
                                                 qbi, kbi, vbi, qkvbias);

  // merged QKV projection -> qkv[N][384] bf16
  gemm_mfma<true><<<gqkv, blk, 0, stream>>>(xbf, qkvWt, qkvbias, qkvb, N, 128, 384);

  // edge pass 1 (hist + bias) -> scans -> pass 2 (XCD-partitioned permute)
  edge_hist_bias<<<dim3(ge), blk, 0, stream>>>(ei, ea, eW, eb, pos, ebias_seq, E);
  deg_block_sum<<<dim3(nb), blk, 0, stream>>>(pos, bsum, N);
  scan_bsum<<<dim3(1), dim3(64), 0, stream>>>(bsum, offs + N, nb);
  deg_scan_write<<<dim3(nb), blk, 0, stream>>>(pos, bsum, offs, pos, N);
  edge_scatter_part<<<dim3(1024), blk, 0, stream>>>(ei, pos, ebias_seq, csr_src, ebp, E, N);

  // fused attention aggregate (one wave per node, static)
  node_agg<<<dim3((N + 3) / 4), blk, 0, stream>>>(csr_src, offs, qkvb, ebp, aggb, N);

  // output projection fused with residual LN1 -> x1bf (bf16 residual from xbf)
  gemm_ln<false, true, true><<<g128, blk, 0, stream>>>(aggb, oWt, ob, xbf,
                                                       ln1_g, ln1_b, nullptr, x1bf, N, 128);

  // FFN: f1 GEMM, LN+GELU, f2 + LN2 -> out
  gemm_mfma<true><<<gf1, blk, 0, stream>>>(x1bf, f1Wt, f1b, hbufb, N, 128, 512);
  ln_gelu512<<<dim3((N + 3) / 4), blk, 0, stream>>>(hbufb, lnf_g, lnf_b, N);
  gemm_ln<true, false, true><<<g128, blk, 0, stream>>>(hbufb, f2Wt, f2b, x1bf,
                                                       ln2_g, ln2_b, out, nullptr, N, 512);
}

// Round 16
// 287.379 us; speedup vs baseline: 1.7641x; 1.0225x over previous
//
#include <hip/hip_runtime.h>
#include <math.h>

#define LN_EPS 1e-5f

typedef __attribute__((ext_vector_type(8))) __bf16 bf16x8;
typedef __attribute__((ext_vector_type(4))) float f32x4;

__device__ inline float bf2f(unsigned short u) {
  union { unsigned int i; float f; } x; x.i = ((unsigned int)u) << 16; return x.f;
}
__device__ inline unsigned short f2bf(float f) {
  union { float f; unsigned int i; } x; x.f = f;
  unsigned int r = (x.i + 0x7FFFu + ((x.i >> 16) & 1u)) >> 16;   // RNE
  return (unsigned short)r;
}
__device__ inline void gload_lds16(const void* g, void* l) {
  __builtin_amdgcn_global_load_lds((const __attribute__((address_space(1))) void*)g,
                                   (__attribute__((address_space(3))) void*)l, 16, 0, 0);
}

// ------- front: to_bf16 ∪ pos-zero ∪ all weight transposes + bias concat, one launch -------
__global__ __launch_bounds__(256)
void front(const float* __restrict__ x, unsigned short* __restrict__ xbf, long n,
           int* __restrict__ pos, int N, int gA, int gZ,
           const float* qW, const float* kW, const float* vW, const float* oW,
           const float* f1W, const float* f2W,
           unsigned short* qkvWt, unsigned short* oWt,
           unsigned short* f1Wt, unsigned short* f2Wt,
           const float* qb, const float* kb, const float* vb, float* qkvbias) {
  const int b = blockIdx.x;
  const int tid = threadIdx.x;
  if (b < gA) {                       // f32 -> bf16
    long i = ((long)b * 256 + tid) * 4;
    if (i >= n) return;
    float4 v = *(const float4*)&x[i];
    ushort4 o = { f2bf(v.x), f2bf(v.y), f2bf(v.z), f2bf(v.w) };
    *(ushort4*)&xbf[i] = o;
    return;
  }
  if (b < gA + gZ) {                  // zero pos[N]
    int base = (b - gA) * 1024 + tid * 4;
    if (base + 3 < N) *(int4*)(pos + base) = make_int4(0, 0, 0, 0);
    else for (int j = 0; j < 4; ++j) if (base + j < N) pos[base + j] = 0;
    return;
  }
  const int t = b - gA - gZ;          // weight prep tiles
  if (t == 192) {
    int i = tid;
    if (i < 128) { qkvbias[i] = qb[i]; qkvbias[128 + i] = kb[i]; }
    else if (i < 256) qkvbias[256 + (i - 128)] = vb[i - 128];
    return;
  }
  const float* W; unsigned short* Wt; int K, M, lt;
  if (t < 64)       { K = 128; M = 128; lt = t & 15;
    if (t < 16)      { W = qW; Wt = qkvWt; }
    else if (t < 32) { W = kW; Wt = qkvWt + 16384; }
    else if (t < 48) { W = vW; Wt = qkvWt + 32768; }
    else             { W = oW; Wt = oWt; } }
  else if (t < 128) { K = 128; M = 512; lt = t - 64; W = f1W; Wt = f1Wt; }
  else              { K = 512; M = 128; lt = t - 128; W = f2W; Wt = f2Wt; }
  const int ktiles = K >> 5;
  const int k0 = (lt % ktiles) * 32, m0 = (lt / ktiles) * 32;
  __shared__ float tb[32][33];
  const int tx = tid & 31, ty = tid >> 5;  // 32 x 8
#pragma unroll
  for (int i = 0; i < 32; i += 8)
    tb[ty + i][tx] = W[(size_t)(k0 + ty + i) * M + m0 + tx];
  __syncthreads();
#pragma unroll
  for (int i = 0; i < 32; i += 8)
    Wt[(size_t)(m0 + ty + i) * K + k0 + tx] = f2bf(tb[tx][ty + i]);
}

// ---------------- bf16 MFMA GEMM: C[N,M] = A[N,K] @ Wt[M,K]^T + bias ----------------
template<bool OBF>
__global__ __launch_bounds__(256)
void gemm_mfma(const unsigned short* __restrict__ A, const unsigned short* __restrict__ Wt,
               const float* __restrict__ bias, void* __restrict__ Cout,
               int Nr, int K, int M) {
  __shared__ __align__(16) unsigned short As[128 * 64];
  __shared__ __align__(16) unsigned short Bs[128 * 64];
  const int tid = threadIdx.x;
  const int bm = blockIdx.x * 128, bn = blockIdx.y * 128;
  const int lane = tid & 63;
  const int wr = (tid >> 6) >> 1, wc = (tid >> 6) & 1;
  f32x4 acc[4][4] = {};
  const int nkt = K >> 6;
  for (int kt = 0; kt < nkt; ++kt) {
#pragma unroll
    for (int i = 0; i < 4; ++i) {
      int c = tid + i * 256;
      int row = c >> 3;
      int j = (c & 7) ^ (row & 7);
      int ar = bm + row; ar = ar < Nr ? ar : Nr - 1;
      gload_lds16(A + (size_t)ar * K + kt * 64 + j * 8, As + (size_t)c * 8);
      gload_lds16(Wt + (size_t)(bn + row) * K + kt * 64 + j * 8, Bs + (size_t)c * 8);
    }
    __syncthreads();
#pragma unroll
    for (int ks = 0; ks < 2; ++ks) {
      bf16x8 af[4], bfr[4];
#pragma unroll
      for (int f = 0; f < 4; ++f) {
        int rowa = wr * 64 + f * 16 + (lane & 15);
        int ja = (ks * 4 + (lane >> 4)) ^ (rowa & 7);
        af[f] = *(const bf16x8*)(As + rowa * 64 + ja * 8);
        int rowb = wc * 64 + f * 16 + (lane & 15);
        int jb = (ks * 4 + (lane >> 4)) ^ (rowb & 7);
        bfr[f] = *(const bf16x8*)(Bs + rowb * 64 + jb * 8);
      }
#pragma unroll
      for (int fr = 0; fr < 4; ++fr)
#pragma unroll
        for (int fc = 0; fc < 4; ++fc)
          acc[fr][fc] = __builtin_amdgcn_mfma_f32_16x16x32_bf16(af[fr], bfr[fc], acc[fr][fc], 0, 0, 0);
    }
    __syncthreads();
  }
#pragma unroll
  for (int fr = 0; fr < 4; ++fr) {
#pragma unroll
    for (int j = 0; j < 4; ++j) {
      int row = bm + wr * 64 + fr * 16 + (lane >> 4) * 4 + j;
      if (row < Nr) {
#pragma unroll
        for (int fc = 0; fc < 4; ++fc) {
          int col = bn + wc * 64 + fc * 16 + (lane & 15);
          float v = acc[fr][fc][j] + bias[col];
          if (OBF) ((unsigned short*)Cout)[(size_t)row * M + col] = f2bf(v);
          else     ((float*)Cout)[(size_t)row * M + col] = v;
        }
      }
    }
  }
}

// ------- bf16 MFMA GEMM (M=128) fused with y = LN(res + A@Wt^T + bias) -------
template<bool WF32, bool WBF, bool RESBF>
__global__ __launch_bounds__(256)
void gemm_ln(const unsigned short* __restrict__ A, const unsigned short* __restrict__ Wt,
             const float* __restrict__ bias, const void* __restrict__ res,
             const float* __restrict__ g, const float* __restrict__ b,
             float* __restrict__ y, unsigned short* __restrict__ ybf, int Nr, int K) {
  __shared__ __align__(16) unsigned short As[128 * 64];
  __shared__ __align__(16) unsigned short Bs[128 * 64];
  __shared__ float pls[128][2], plss[128][2];
  const int tid = threadIdx.x;
  const int bm = blockIdx.x * 128;
  const int lane = tid & 63;
  const int wr = (tid >> 6) >> 1, wc = (tid >> 6) & 1;
  f32x4 acc[4][4] = {};
  const int nkt = K >> 6;
  for (int kt = 0; kt < nkt; ++kt) {
#pragma unroll
    for (int i = 0; i < 4; ++i) {
      int c = tid + i * 256;
      int row = c >> 3;
      int j = (c & 7) ^ (row & 7);
      int ar = bm + row; ar = ar < Nr ? ar : Nr - 1;
      gload_lds16(A + (size_t)ar * K + kt * 64 + j * 8, As + (size_t)c * 8);
      gload_lds16(Wt + (size_t)row * K + kt * 64 + j * 8, Bs + (size_t)c * 8);
    }
    __syncthreads();
#pragma unroll
    for (int ks = 0; ks < 2; ++ks) {
      bf16x8 af[4], bfr[4];
#pragma unroll
      for (int f = 0; f < 4; ++f) {
        int rowa = wr * 64 + f * 16 + (lane & 15);
        int ja = (ks * 4 + (lane >> 4)) ^ (rowa & 7);
        af[f] = *(const bf16x8*)(As + rowa * 64 + ja * 8);
        int rowb = wc * 64 + f * 16 + (lane & 15);
        int jb = (ks * 4 + (lane >> 4)) ^ (rowb & 7);
        bfr[f] = *(const bf16x8*)(Bs + rowb * 64 + jb * 8);
      }
#pragma unroll
      for (int fr = 0; fr < 4; ++fr)
#pragma unroll
        for (int fc = 0; fc < 4; ++fc)
          acc[fr][fc] = __builtin_amdgcn_mfma_f32_16x16x32_bf16(af[fr], bfr[fc], acc[fr][fc], 0, 0, 0);
    }
    __syncthreads();
  }
#pragma unroll
  for (int fr = 0; fr < 4; ++fr) {
#pragma unroll
    for (int j = 0; j < 4; ++j) {
      const int rl = wr * 64 + fr * 16 + (lane >> 4) * 4 + j;
      const int row = bm + rl;
      const int rowc = row < Nr ? row : Nr - 1;
      float s = 0.f, ss = 0.f;
#pragma unroll
      for (int fc = 0; fc < 4; ++fc) {
        int col = wc * 64 + fc * 16 + (lane & 15);
        float rv = RESBF ? bf2f(((const unsigned short*)res)[(size_t)rowc * 128 + col])
                         : ((const float*)res)[(size_t)rowc * 128 + col];
        float val = acc[fr][fc][j] + bias[col] + rv;
        acc[fr][fc][j] = val;
        s += val; ss += val * val;
      }
      s += __shfl_xor(s, 1); ss += __shfl_xor(ss, 1);
      s += __shfl_xor(s, 2); ss += __shfl_xor(ss, 2);
      s += __shfl_xor(s, 4); ss += __shfl_xor(ss, 4);
      s += __shfl_xor(s, 8); ss += __shfl_xor(ss, 8);
      if ((lane & 15) == 0) { pls[rl][wc] = s; plss[rl][wc] = ss; }
    }
  }
  __syncthreads();
#pragma unroll
  for (int fr = 0; fr < 4; ++fr) {
#pragma unroll
    for (int j = 0; j < 4; ++j) {
      const int rl = wr * 64 + fr * 16 + (lane >> 4) * 4 + j;
      const int row = bm + rl;
      if (row >= Nr) continue;
      const float S = pls[rl][0] + pls[rl][1];
      const float SS = plss[rl][0] + plss[rl][1];
      const float mu = S * (1.f / 128.f);
      const float inv = rsqrtf(SS * (1.f / 128.f) - mu * mu + LN_EPS);
#pragma unroll
      for (int fc = 0; fc < 4; ++fc) {
        int col = wc * 64 + fc * 16 + (lane & 15);
        float o = (acc[fr][fc][j] - mu) * inv * g[col] + b[col];
        if (WF32) y[(size_t)row * 128 + col] = o;
        if (WBF)  ybf[(size_t)row * 128 + col] = f2bf(o);
      }
    }
  }
}

// ---------------- edge pass 1: histogram + edge bias (coalesced) ----------------
__global__ __launch_bounds__(256)
void edge_hist_bias(const int* __restrict__ ei, const float* __restrict__ ea,
                    const float* __restrict__ eW, const float* __restrict__ eb,
                    int* __restrict__ deg, unsigned short* __restrict__ ebias_seq, int E) {
  __shared__ float ews[256];
  __shared__ float ebs[8];
  const int tid = threadIdx.x;
  if (tid < 256) ews[tid] = eW[tid];
  if (tid < 8) ebs[tid] = eb[tid];
  __syncthreads();
  int e = blockIdx.x * 256 + tid;
  if (e >= E) return;
  atomicAdd(&deg[ei[E + e]], 1);
  float bias[8];
#pragma unroll
  for (int h = 0; h < 8; ++h) bias[h] = ebs[h];
#pragma unroll
  for (int i4 = 0; i4 < 8; ++i4) {
    float4 a = *(const float4*)&ea[(size_t)e * 32 + i4 * 4];
    float av[4] = {a.x, a.y, a.z, a.w};
#pragma unroll
    for (int j = 0; j < 4; ++j)
#pragma unroll
      for (int h = 0; h < 8; ++h) bias[h] += av[j] * ews[(i4 * 4 + j) * 8 + h];
  }
  union { unsigned short us[8]; uint4 v; } pk;
#pragma unroll
  for (int h = 0; h < 8; ++h) pk.us[h] = f2bf(bias[h]);
  *(uint4*)&ebias_seq[(size_t)e * 8] = pk.v;
}

__global__ __launch_bounds__(256)
void deg_block_sum(const int* __restrict__ deg, int* __restrict__ bsum, int N) {
  const int t = threadIdx.x;
  const int beg = blockIdx.x * 2048 + t * 8;
  int s = 0;
#pragma unroll
  for (int j = 0; j < 8; ++j) { int i = beg + j; if (i < N) s += deg[i]; }
#pragma unroll
  for (int off = 32; off; off >>= 1) s += __shfl_xor(s, off);
  __shared__ int ws[4];
  if ((t & 63) == 0) ws[t >> 6] = s;
  __syncthreads();
  if (t == 0) bsum[blockIdx.x] = ws[0] + ws[1] + ws[2] + ws[3];
}

__global__ __launch_bounds__(64)
void scan_bsum(int* __restrict__ bsum, int* __restrict__ offs_last, int nb) {
  const int t = threadIdx.x;
  int v = (t < nb) ? bsum[t] : 0;
  int inc = v;
#pragma unroll
  for (int off = 1; off < 64; off <<= 1) {
    int x = __shfl_up(inc, off);
    if (t >= off) inc += x;
  }
  if (t < nb) bsum[t] = inc - v;
  if (t == 63) *offs_last = inc;
}

__global__ __launch_bounds__(256)
void deg_scan_write(const int* __restrict__ deg, const int* __restrict__ bsum,
                    int* __restrict__ offs, int* __restrict__ pos, int N) {
  const int t = threadIdx.x;
  const int beg = blockIdx.x * 2048 + t * 8;
  int loc[8]; int T = 0;
#pragma unroll
  for (int j = 0; j < 8; ++j) { int i = beg + j; loc[j] = (i < N) ? deg[i] : 0; T += loc[j]; }
  int inc = T;
#pragma unroll
  for (int off = 1; off < 64; off <<= 1) {
    int x = __shfl_up(inc, off);
    if ((t & 63) >= off) inc += x;
  }
  __shared__ int ws[4];
  if ((t & 63) == 63) ws[t >> 6] = inc;
  __syncthreads();
  const int wid = t >> 6;
  int wbase = 0;
  for (int w = 0; w < wid; ++w) wbase += ws[w];
  int base = bsum[blockIdx.x] + wbase + inc - T;
#pragma unroll
  for (int j = 0; j < 8; ++j) {
    int i = beg + j;
    if (i < N) { offs[i] = base; pos[i] = base; base += loc[j]; }
  }
}

// ------- edge pass 2: XCD-partitioned permute of (src, bias) into CSR order -------
__global__ __launch_bounds__(256)
void edge_scatter_part(const int* __restrict__ ei, int* __restrict__ pos,
                       const unsigned short* __restrict__ ebias_seq,
                       int* __restrict__ csr_src, unsigned short* __restrict__ ebp,
                       int E, int N) {
  const int part = blockIdx.x & 7;
  const int slice = blockIdx.x >> 3;
  const int nslice = gridDim.x >> 3;
  const int per = (E + nslice - 1) / nslice;
  const int lo = slice * per;
  const int hi = min(E, lo + per);
  const int drange = (N + 7) >> 3;
  const int dlo = part * drange;
  const int dhi = min(N, dlo + drange);
  for (int e = lo + threadIdx.x; e < hi; e += 256) {
    int d = ei[E + e];
    if (d < dlo || d >= dhi) continue;
    int s = ei[e];
    uint4 bi = *(const uint4*)&ebias_seq[(size_t)e * 8];
    int p = atomicAdd(&pos[d], 1);
    csr_src[p] = s;
    *(uint4*)&ebp[(size_t)p * 8] = bi;
  }
}

// ---------------- fused per-node attention aggregate (8/4/1 ladder) ----------------
__global__ __launch_bounds__(256)
void node_agg(const int* __restrict__ csr_src, const int* __restrict__ offs,
              const unsigned short* __restrict__ qkv, const unsigned short* __restrict__ ebp,
              unsigned short* __restrict__ agg, int N) {
  const int wid = threadIdx.x >> 6, lane = threadIdx.x & 63;
  const int h = lane >> 3;
  const long n = (long)blockIdx.x * 4 + wid;
  if (n >= N) return;
  const int off = offs[n], end = offs[n + 1];
  const ushort2 kv2 = *(const ushort2*)&qkv[(size_t)n * 384 + 128 + lane * 2];
  const float k0 = bf2f(kv2.x), k1 = bf2f(kv2.y);
  float acc0 = 0.f, acc1 = 0.f, den = 0.f;
  int i = off;
  for (; i + 8 <= end; i += 8) {       // 8-wide: 16 independent q/v gathers in flight
    size_t bb[8];
#pragma unroll
    for (int u = 0; u < 8; ++u) bb[u] = (size_t)csr_src[i + u] * 384;
    ushort2 qv[8], vv[8];
#pragma unroll
    for (int u = 0; u < 8; ++u) qv[u] = *(const ushort2*)&qkv[bb[u] + lane * 2];
#pragma unroll
    for (int u = 0; u < 8; ++u) vv[u] = *(const ushort2*)&qkv[bb[u] + 256 + lane * 2];
    float ebv[8];
#pragma unroll
    for (int u = 0; u < 8; ++u) ebv[u] = bf2f(ebp[(size_t)(i + u) * 8 + h]);
    float p[8];
#pragma unroll
    for (int u = 0; u < 8; ++u) p[u] = bf2f(qv[u].x) * k0 + bf2f(qv[u].y) * k1;
#pragma unroll
    for (int u = 0; u < 8; ++u) {
      p[u] += __shfl_xor(p[u], 1);
      p[u] += __shfl_xor(p[u], 2);
      p[u] += __shfl_xor(p[u], 4);
    }
#pragma unroll
    for (int u = 0; u < 8; ++u) {
      const float ex = __expf(p[u] * 0.25f + ebv[u]);
      den += ex;
      acc0 += bf2f(vv[u].x) * ex;
      acc1 += bf2f(vv[u].y) * ex;
    }
  }
  for (; i + 4 <= end; i += 4) {
    size_t bb[4];
#pragma unroll
    for (int u = 0; u < 4; ++u) bb[u] = (size_t)csr_src[i + u] * 384;
    ushort2 qv[4], vv[4];
#pragma unroll
    for (int u = 0; u < 4; ++u) qv[u] = *(const ushort2*)&qkv[bb[u] + lane * 2];
#pragma unroll
    for (int u = 0; u < 4; ++u) vv[u] = *(const ushort2*)&qkv[bb[u] + 256 + lane * 2];
    float ebv[4];
#pragma unroll
    for (int u = 0; u < 4; ++u) ebv[u] = bf2f(ebp[(size_t)(i + u) * 8 + h]);
    float p[4];
#pragma unroll
    for (int u = 0; u < 4; ++u) p[u] = bf2f(qv[u].x) * k0 + bf2f(qv[u].y) * k1;
#pragma unroll
    for (int u = 0; u < 4; ++u) {
      p[u] += __shfl_xor(p[u], 1);
      p[u] += __shfl_xor(p[u], 2);
      p[u] += __shfl_xor(p[u], 4);
    }
#pragma unroll
    for (int u = 0; u < 4; ++u) {
      const float ex = __expf(p[u] * 0.25f + ebv[u]);
      den += ex;
      acc0 += bf2f(vv[u].x) * ex;
      acc1 += bf2f(vv[u].y) * ex;
    }
  }
  for (; i < end; ++i) {
    const size_t b0 = (size_t)csr_src[i] * 384;
    const ushort2 qa = *(const ushort2*)&qkv[b0 + lane * 2];
    const ushort2 va = *(const ushort2*)&qkv[b0 + 256 + lane * 2];
    float p = bf2f(qa.x) * k0 + bf2f(qa.y) * k1;
    p += __shfl_xor(p, 1);
    p += __shfl_xor(p, 2);
    p += __shfl_xor(p, 4);
    const float ex = __expf(p * 0.25f + bf2f(ebp[(size_t)i * 8 + h]));
    den += ex;
    acc0 += bf2f(va.x) * ex;
    acc1 += bf2f(va.y) * ex;
  }
  const float r = 1.f / fmaxf(den, 1e-8f);
  ushort2 o; o.x = f2bf(acc0 * r); o.y = f2bf(acc1 * r);
  *(ushort2*)&agg[(size_t)n * 128 + lane * 2] = o;
}

// ---------------- wave-per-row LN(512) -> exact GELU, bf16, uint4 loads ----------------
__global__ __launch_bounds__(256)
void ln_gelu512(unsigned short* __restrict__ hbuf, const float* __restrict__ g,
                const float* __restrict__ b, int Nr) {
  const int wid = threadIdx.x >> 6, lane = threadIdx.x & 63;
  const long row = (long)blockIdx.x * 4 + wid;
  if (row >= Nr) return;
  union { uint4 v; unsigned short us[8]; } u;
  u.v = *(const uint4*)&hbuf[row * 512 + lane * 8];
  float f[8];
  float s = 0.f, ss = 0.f;
#pragma unroll
  for (int j = 0; j < 8; ++j) { f[j] = bf2f(u.us[j]); s += f[j]; ss += f[j] * f[j]; }
#pragma unroll
  for (int off = 32; off; off >>= 1) { s += __shfl_xor(s, off); ss += __shfl_xor(ss, off); }
  const float mu = s * (1.f / 512.f);
  const float inv = rsqrtf(ss * (1.f / 512.f) - mu * mu + LN_EPS);
  float4 g0 = *(const float4*)&g[lane * 8];
  float4 g1 = *(const float4*)&g[lane * 8 + 4];
  float4 b0 = *(const float4*)&b[lane * 8];
  float4 b1 = *(const float4*)&b[lane * 8 + 4];
  float gv[8] = {g0.x, g0.y, g0.z, g0.w, g1.x, g1.y, g1.z, g1.w};
  float bv[8] = {b0.x, b0.y, b0.z, b0.w, b1.x, b1.y, b1.z, b1.w};
#pragma unroll
  for (int j = 0; j < 8; ++j) {
    float t = (f[j] - mu) * inv * gv[j] + bv[j];
    t = 0.5f * t * (1.f + erff(t * 0.70710678118654752f));
    u.us[j] = f2bf(t);
  }
  *(uint4*)&hbuf[row * 512 + lane * 8] = u.v;
}

extern "C" void kernel_launch(void* const* d_in, const int* in_sizes, int n_in,
                              void* d_out, int out_size, void* d_ws, size_t ws_size,
                              hipStream_t stream) {
  const float* x   = (const float*)d_in[0];
  const int*   ei  = (const int*)d_in[1];
  const float* ea  = (const float*)d_in[2];
  const float* qW  = (const float*)d_in[3];
  const float* qbi = (const float*)d_in[4];
  const float* kW  = (const float*)d_in[5];
  const float* kbi = (const float*)d_in[6];
  const float* vW  = (const float*)d_in[7];
  const float* vbi = (const float*)d_in[8];
  const float* eW  = (const float*)d_in[9];
  const float* eb  = (const float*)d_in[10];
  const float* oW  = (const float*)d_in[11];
  const float* ob  = (const float*)d_in[12];
  const float* ln1_g = (const float*)d_in[13];
  const float* ln1_b = (const float*)d_in[14];
  const float* f1W = (const float*)d_in[15];
  const float* f1b = (const float*)d_in[16];
  const float* lnf_g = (const float*)d_in[17];
  const float* lnf_b = (const float*)d_in[18];
  const float* f2W = (const float*)d_in[19];
  const float* f2b = (const float*)d_in[20];
  const float* ln2_g = (const float*)d_in[21];
  const float* ln2_b = (const float*)d_in[22];
  float* out = (float*)d_out;

  const int N = in_sizes[0] / 128;
  const int E = in_sizes[1] / 2;
  const size_t NH = (size_t)N * 128;   // 6.4M floats

  // workspace (float units), lifetime-overlapped:
  //  [0, .5NH)      xbf bf16 -> x1bf
  //  [.5NH, 2NH)    qkv bf16 [N][384]; hbuf bf16 [N][512] overlays [.5NH, 2.5NH) (FFN)
  //  [2NH, 2.5NH)   ebp bf16 [E][8] (dead before f1)
  //  [2.5NH, 3NH)   aggb bf16
  //  [3NH, 3.5NH)   ebias_seq bf16 [E][8]
  //  [4NH, ...)     ints: csr_src E, offs N+1, pos N, bsum; then bf16 weights + bias
  float* F = (float*)d_ws;
  unsigned short* xbf   = (unsigned short*)F;
  unsigned short* qkvb  = (unsigned short*)(F + NH / 2);
  unsigned short* ebp   = (unsigned short*)(F + 2 * NH);
  unsigned short* aggb  = (unsigned short*)(F + 2 * NH + NH / 2);
  unsigned short* ebias_seq = (unsigned short*)(F + 3 * NH);
  unsigned short* x1bf  = xbf;
  unsigned short* hbufb = (unsigned short*)(F + NH / 2);
  int* ib      = (int*)(F + 4 * NH);
  int* csr_src = ib;
  int* offs    = ib + E;
  int* pos     = ib + E + N + 1;
  int* bsum    = ib + E + 2 * N + 1;
  unsigned short* wt = (unsigned short*)(ib + E + 2 * N + 128);
  unsigned short* qkvWt = wt;            // 384x128
  unsigned short* oWt   = wt + 49152;    // 128x128
  unsigned short* f1Wt  = wt + 65536;    // 512x128
  unsigned short* f2Wt  = wt + 131072;   // 128x512
  float* qkvbias = (float*)(wt + 196608);

  dim3 blk(256);
  dim3 gqkv((N + 127) / 128, 3);
  dim3 g128((N + 127) / 128, 1);
  dim3 gf1((N + 127) / 128, 4);
  const int nb = (N + 2047) / 2048;
  const int ge = (E + 255) / 256;
  const int gA = (int)((NH / 4 + 255) / 256);
  const int gZ = (N + 1023) / 1024;

  // front: to_bf16 + pos-zero + all weight prep in ONE launch
  front<<<dim3(gA + gZ + 193), blk, 0, stream>>>(x, xbf, (long)NH, pos, N, gA, gZ,
                                                 qW, kW, vW, oW, f1W, f2W,
                                                 qkvWt, oWt, f1Wt, f2Wt,
                                                 qbi, kbi, vbi, qkvbias);

  // merged QKV projection -> qkv[N][384] bf16
  gemm_mfma<true><<<gqkv, blk, 0, stream>>>(xbf, qkvWt, qkvbias, qkvb, N, 128, 384);

  // edge pass 1 (hist + bias) -> scans -> pass 2 (XCD-partitioned permute)
  edge_hist_bias<<<dim3(ge), blk, 0, stream>>>(ei, ea, eW, eb, pos, ebias_seq, E);
  deg_block_sum<<<dim3(nb), blk, 0, stream>>>(pos, bsum, N);
  scan_bsum<<<dim3(1), dim3(64), 0, stream>>>(bsum, offs + N, nb);
  deg_scan_write<<<dim3(nb), blk, 0, stream>>>(pos, bsum, offs, pos, N);
  edge_scatter_part<<<dim3(1024), blk, 0, stream>>>(ei, pos, ebias_seq, csr_src, ebp, E, N);

  // fused attention aggregate (one wave per node, static)
  node_agg<<<dim3((N + 3) / 4), blk, 0, stream>>>(csr_src, offs, qkvb, ebp, aggb, N);

  // output projection fused with residual LN1 -> x1bf (bf16 residual from xbf)
  gemm_ln<false, true, true><<<g128, blk, 0, stream>>>(aggb, oWt, ob, xbf,
                                                       ln1_g, ln1_b, nullptr, x1bf, N, 128);

  // FFN: f1 GEMM, LN+GELU, f2 + LN2 -> out
  gemm_mfma<true><<<gf1, blk, 0, stream>>>(x1bf, f1Wt, f1b, hbufb, N, 128, 512);
  ln_gelu512<<<dim3((N + 3) / 4), blk, 0, stream>>>(hbufb, lnf_g, lnf_b, N);
  gemm_ln<true, false, true><<<g128, blk, 0, stream>>>(hbufb, f2Wt, f2b, x1bf,
                                                       ln2_g, ln2_b, out, nullptr, N, 512);
}